// Round 1
// baseline (12611.574 us; speedup 1.0000x reference)
//
#include <hip/hip_runtime.h>

#define FD 128

static inline size_t roundup256(size_t x) { return (x + 255) & ~(size_t)255; }

// ---------------------------------------------------------------------------
// GEMM: H[nrows,128] = X[nrows,128] @ W[128,128], fused al_s = H.a_s, al_d = H.a_d
// Block: 256 threads = 8 row-groups x 32 lanes; each lane owns 4 output cols.
// W staged in LDS (64KB); X staged 8 rows at a time (4KB). 64 rows per block.
// ---------------------------------------------------------------------------
__global__ __launch_bounds__(256) void gemm_al_kernel(
    const float* __restrict__ X, const float* __restrict__ W,
    const float* __restrict__ a_s, const float* __restrict__ a_d,
    float* __restrict__ H, float* __restrict__ als, float* __restrict__ ald,
    int nrows)
{
    __shared__ float Wl[FD * FD];
    __shared__ float Xl[8][FD];
    const int tid = threadIdx.x;
    for (int i = tid * 4; i < FD * FD; i += 256 * 4)
        *(float4*)&Wl[i] = *(const float4*)&W[i];
    const int rg   = tid >> 5;
    const int lane = tid & 31;
    const int rowBase = blockIdx.x * 64;
    const float4 as4 = *(const float4*)&a_s[lane * 4];
    const float4 ad4 = *(const float4*)&a_d[lane * 4];
    __syncthreads();
    for (int chunk = 0; chunk < 8; ++chunk) {
        const int r0 = rowBase + chunk * 8;
        {
            const int rr = tid >> 5;
            const int cc = (tid & 31) * 4;
            const int gr = r0 + rr;
            float4 v = make_float4(0.f, 0.f, 0.f, 0.f);
            if (gr < nrows) v = *(const float4*)&X[(size_t)gr * FD + cc];
            *(float4*)&Xl[rr][cc] = v;
        }
        __syncthreads();
        float a0 = 0.f, a1 = 0.f, a2 = 0.f, a3 = 0.f;
        #pragma unroll 16
        for (int k = 0; k < FD; ++k) {
            const float xv = Xl[rg][k];
            const float4 w4 = *(const float4*)&Wl[k * FD + lane * 4];
            a0 = fmaf(xv, w4.x, a0);
            a1 = fmaf(xv, w4.y, a1);
            a2 = fmaf(xv, w4.z, a2);
            a3 = fmaf(xv, w4.w, a3);
        }
        const int gr = r0 + rg;
        if (gr < nrows) {
            *(float4*)&H[(size_t)gr * FD + lane * 4] = make_float4(a0, a1, a2, a3);
            float ps = a0 * as4.x + a1 * as4.y + a2 * as4.z + a3 * as4.w;
            float pd = a0 * ad4.x + a1 * ad4.y + a2 * ad4.z + a3 * ad4.w;
            #pragma unroll
            for (int off = 16; off; off >>= 1) {
                ps += __shfl_down(ps, off, 32);
                pd += __shfl_down(pd, off, 32);
            }
            if (lane == 0) { als[gr] = ps; ald[gr] = pd; }
        }
        __syncthreads();
    }
}

// float -> order-preserving unsigned (sign-magnitude trick)
__device__ __forceinline__ unsigned f2ord(float f) {
    unsigned u = __float_as_uint(f);
    return (u >> 31) ? ~u : (u | 0x80000000u);
}
__device__ __forceinline__ float ord2f(unsigned o) {
    return __uint_as_float((o >> 31) ? (o & 0x7FFFFFFFu) : ~o);
}

// Pass A: e = leakyrelu(al_s[src]+al_d[dst]); store; atomicMax per dst
__global__ __launch_bounds__(256) void edge_max_kernel(
    const int* __restrict__ esrc, const int* __restrict__ edst,
    const float* __restrict__ als, const float* __restrict__ ald,
    float* __restrict__ ebuf, unsigned* __restrict__ mord,
    int E, int total)
{
    int k = blockIdx.x * blockDim.x + threadIdx.x;
    if (k >= total) return;
    int s, d;
    if (k < E) { s = esrc[k]; d = edst[k]; } else { s = d = k - E; }
    float e = als[s] + ald[d];
    e = (e >= 0.f) ? e : 0.2f * e;
    ebuf[k] = e;
    atomicMax(&mord[d], f2ord(e));
}

// Pass B: ex = exp(e - m[dst]); store; denom[dst] += ex
__global__ __launch_bounds__(256) void edge_exp_kernel(
    const int* __restrict__ edst, const unsigned* __restrict__ mord,
    float* __restrict__ ebuf, float* __restrict__ denom,
    int E, int total)
{
    int k = blockIdx.x * blockDim.x + threadIdx.x;
    if (k >= total) return;
    int d = (k < E) ? edst[k] : k - E;
    float m = ord2f(mord[d]);
    float ex = expf(ebuf[k] - m);
    ebuf[k] = ex;
    unsafeAtomicAdd(&denom[d], ex);
}

// Pass C: out[dst,:] += ex * h[src,:]; 32 lanes per edge, float4 per lane
__global__ __launch_bounds__(256) void edge_scatter_kernel(
    const int* __restrict__ esrc, const int* __restrict__ edst,
    const float* __restrict__ ebuf, const float* __restrict__ H,
    float* __restrict__ out, int E, int total)
{
    int grp  = (int)((blockIdx.x * (unsigned)blockDim.x + threadIdx.x) >> 5);
    int lane = threadIdx.x & 31;
    if (grp >= total) return;
    int s, d;
    if (grp < E) { s = esrc[grp]; d = edst[grp]; } else { s = d = grp - E; }
    float w = ebuf[grp];
    float4 hv = *(const float4*)&H[(size_t)s * FD + lane * 4];
    float* op = &out[(size_t)d * FD + lane * 4];
    unsafeAtomicAdd(op + 0, w * hv.x);
    unsafeAtomicAdd(op + 1, w * hv.y);
    unsafeAtomicAdd(op + 2, w * hv.z);
    unsafeAtomicAdd(op + 3, w * hv.w);
}

// Finalize: out = relu(out/denom + b), float4 per thread
__global__ __launch_bounds__(256) void finalize_kernel(
    float* __restrict__ out, const float* __restrict__ denom,
    const float* __restrict__ b, int n)
{
    int i = blockIdx.x * blockDim.x + threadIdx.x;
    if (i >= n * 32) return;
    int node = i >> 5;
    int c4 = (i & 31) * 4;
    float inv = 1.f / denom[node];
    float4 v = *(float4*)&out[(size_t)node * FD + c4];
    float4 bb = *(const float4*)&b[c4];
    v.x = fmaxf(fmaf(v.x, inv, bb.x), 0.f);
    v.y = fmaxf(fmaf(v.y, inv, bb.y), 0.f);
    v.z = fmaxf(fmaf(v.z, inv, bb.z), 0.f);
    v.w = fmaxf(fmaf(v.w, inv, bb.w), 0.f);
    *(float4*)&out[(size_t)node * FD + c4] = v;
}

// Mean-pool per graph; batch is sorted ascending. One block per graph, 128 threads.
__global__ __launch_bounds__(128) void pool_mean_kernel(
    const float* __restrict__ H, const int* __restrict__ batch,
    float* __restrict__ pooled, int n)
{
    int g = blockIdx.x;
    int lo = 0, hi = n;
    while (lo < hi) { int mid = (lo + hi) >> 1; if (batch[mid] < g) lo = mid + 1; else hi = mid; }
    int start = lo;
    hi = n;
    while (lo < hi) { int mid = (lo + hi) >> 1; if (batch[mid] < g + 1) lo = mid + 1; else hi = mid; }
    int end = lo;
    int col = threadIdx.x;
    float acc = 0.f;
    for (int i = start; i < end; ++i) acc += H[(size_t)i * FD + col];
    float cnt = (float)(end - start);
    pooled[(size_t)g * FD + col] = acc / fmaxf(cnt, 1.f);
}

// logits = [bu | td] @ fc_W + fc_b ; log_softmax over 4 classes. 1 thread/graph.
__global__ __launch_bounds__(256) void fc_logsoftmax_kernel(
    const float* __restrict__ bu, const float* __restrict__ td,
    const float* __restrict__ Wf, const float* __restrict__ bf,
    float* __restrict__ out, int g)
{
    int gid = blockIdx.x * blockDim.x + threadIdx.x;
    if (gid >= g) return;
    float l0 = bf[0], l1 = bf[1], l2 = bf[2], l3 = bf[3];
    for (int k = 0; k < FD; ++k) {
        float v = bu[(size_t)gid * FD + k];
        l0 = fmaf(v, Wf[k * 4 + 0], l0);
        l1 = fmaf(v, Wf[k * 4 + 1], l1);
        l2 = fmaf(v, Wf[k * 4 + 2], l2);
        l3 = fmaf(v, Wf[k * 4 + 3], l3);
    }
    for (int k = 0; k < FD; ++k) {
        float v = td[(size_t)gid * FD + k];
        l0 = fmaf(v, Wf[(FD + k) * 4 + 0], l0);
        l1 = fmaf(v, Wf[(FD + k) * 4 + 1], l1);
        l2 = fmaf(v, Wf[(FD + k) * 4 + 2], l2);
        l3 = fmaf(v, Wf[(FD + k) * 4 + 3], l3);
    }
    float m = fmaxf(fmaxf(l0, l1), fmaxf(l2, l3));
    float ssum = expf(l0 - m) + expf(l1 - m) + expf(l2 - m) + expf(l3 - m);
    float ls = logf(ssum);
    out[(size_t)gid * 4 + 0] = l0 - m - ls;
    out[(size_t)gid * 4 + 1] = l1 - m - ls;
    out[(size_t)gid * 4 + 2] = l2 - m - ls;
    out[(size_t)gid * 4 + 3] = l3 - m - ls;
}

extern "C" void kernel_launch(void* const* d_in, const int* in_sizes, int n_in,
                              void* d_out, int out_size, void* d_ws, size_t ws_size,
                              hipStream_t stream)
{
    const float* x      = (const float*)d_in[0];
    const int*   td_ei  = (const int*)d_in[1];
    const int*   bu_ei  = (const int*)d_in[2];
    const int*   batch  = (const int*)d_in[3];
    const float* fc_W   = (const float*)d_in[20];
    const float* fc_b   = (const float*)d_in[21];

    const int N = in_sizes[0] / FD;
    const int E = in_sizes[1] / 2;
    const int G = out_size / 4;
    const int total = E + N;

    // workspace layout
    char* p = (char*)d_ws;
    float* bufA = (float*)p;  p += roundup256((size_t)N * FD * 4);
    float* bufB = (float*)p;  p += roundup256((size_t)N * FD * 4);
    float* als  = (float*)p;  p += roundup256((size_t)N * 4);
    float* ald  = (float*)p;  p += roundup256((size_t)N * 4);
    unsigned* mord = (unsigned*)p; p += roundup256((size_t)N * 4);
    float* denom = (float*)p; p += roundup256((size_t)N * 4);
    float* ebuf  = (float*)p; p += roundup256((size_t)total * 4);
    float* pooled_td = (float*)p; p += roundup256((size_t)G * FD * 4);
    float* pooled_bu = (float*)p; p += roundup256((size_t)G * FD * 4);

    const dim3 blk256(256), blk128(128);
    const dim3 gGemm((N + 63) / 64);
    const dim3 gEdge((total + 255) / 256);
    const dim3 gScat((unsigned)(((size_t)total * 32 + 255) / 256));
    const dim3 gFin(((size_t)N * 32 + 255) / 256);

    auto run_layer = [&](const float* Xin, const int* ei,
                         const float* W, const float* as_, const float* ad_, const float* b_,
                         float* hbuf, float* obuf) {
        const int* esrc = ei;
        const int* edst = ei + E;
        gemm_al_kernel<<<gGemm, blk256, 0, stream>>>(Xin, W, as_, ad_, hbuf, als, ald, N);
        hipMemsetAsync(mord, 0, (size_t)N * 4, stream);
        hipMemsetAsync(denom, 0, (size_t)N * 4, stream);
        hipMemsetAsync(obuf, 0, (size_t)N * FD * 4, stream);
        edge_max_kernel<<<gEdge, blk256, 0, stream>>>(esrc, edst, als, ald, ebuf, mord, E, total);
        edge_exp_kernel<<<gEdge, blk256, 0, stream>>>(edst, mord, ebuf, denom, E, total);
        edge_scatter_kernel<<<gScat, blk256, 0, stream>>>(esrc, edst, ebuf, hbuf, obuf, E, total);
        finalize_kernel<<<gFin, blk256, 0, stream>>>(obuf, denom, b_, N);
    };

    auto run_branch = [&](const int* ei, int base, float* pooled) {
        const float* W1  = (const float*)d_in[base + 0];
        const float* as1 = (const float*)d_in[base + 1];
        const float* ad1 = (const float*)d_in[base + 2];
        const float* b1  = (const float*)d_in[base + 3];
        const float* W2  = (const float*)d_in[base + 4];
        const float* as2 = (const float*)d_in[base + 5];
        const float* ad2 = (const float*)d_in[base + 6];
        const float* b2  = (const float*)d_in[base + 7];
        // layer 1: x -> bufA (h), aggregate -> bufB, finalize in place
        run_layer(x, ei, W1, as1, ad1, b1, bufA, bufB);
        // layer 2: bufB -> bufA (h), aggregate -> bufB (zeroed after GEMM reads it)
        run_layer(bufB, ei, W2, as2, ad2, b2, bufA, bufB);
        pool_mean_kernel<<<dim3(G), blk128, 0, stream>>>(bufB, batch, pooled, N);
    };

    run_branch(td_ei, 4, pooled_td);
    run_branch(bu_ei, 12, pooled_bu);

    fc_logsoftmax_kernel<<<dim3((G + 255) / 256), blk256, 0, stream>>>(
        pooled_bu, pooled_td, fc_W, fc_b, (float*)d_out, G);
}

// Round 2
// 1433.287 us; speedup vs baseline: 8.7991x; 8.7991x over previous
//
#include <hip/hip_runtime.h>

#define FD 128
#define SB 512

static inline size_t roundup256(size_t x) { return (x + 255) & ~(size_t)255; }

// ---------------------------------------------------------------------------
// GEMM: H[nrows,128] = X[nrows,128] @ W[128,128], fused al_s = H.a_s, al_d = H.a_d
// ---------------------------------------------------------------------------
__global__ __launch_bounds__(256) void gemm_al_kernel(
    const float* __restrict__ X, const float* __restrict__ W,
    const float* __restrict__ a_s, const float* __restrict__ a_d,
    float* __restrict__ H, float* __restrict__ als, float* __restrict__ ald,
    int nrows)
{
    __shared__ float Wl[FD * FD];
    __shared__ float Xl[8][FD];
    const int tid = threadIdx.x;
    for (int i = tid * 4; i < FD * FD; i += 256 * 4)
        *(float4*)&Wl[i] = *(const float4*)&W[i];
    const int rg   = tid >> 5;
    const int lane = tid & 31;
    const int rowBase = blockIdx.x * 64;
    const float4 as4 = *(const float4*)&a_s[lane * 4];
    const float4 ad4 = *(const float4*)&a_d[lane * 4];
    __syncthreads();
    for (int chunk = 0; chunk < 8; ++chunk) {
        const int r0 = rowBase + chunk * 8;
        {
            const int rr = tid >> 5;
            const int cc = (tid & 31) * 4;
            const int gr = r0 + rr;
            float4 v = make_float4(0.f, 0.f, 0.f, 0.f);
            if (gr < nrows) v = *(const float4*)&X[(size_t)gr * FD + cc];
            *(float4*)&Xl[rr][cc] = v;
        }
        __syncthreads();
        float a0 = 0.f, a1 = 0.f, a2 = 0.f, a3 = 0.f;
        #pragma unroll 16
        for (int k = 0; k < FD; ++k) {
            const float xv = Xl[rg][k];
            const float4 w4 = *(const float4*)&Wl[k * FD + lane * 4];
            a0 = fmaf(xv, w4.x, a0);
            a1 = fmaf(xv, w4.y, a1);
            a2 = fmaf(xv, w4.z, a2);
            a3 = fmaf(xv, w4.w, a3);
        }
        const int gr = r0 + rg;
        if (gr < nrows) {
            *(float4*)&H[(size_t)gr * FD + lane * 4] = make_float4(a0, a1, a2, a3);
            float ps = a0 * as4.x + a1 * as4.y + a2 * as4.z + a3 * as4.w;
            float pd = a0 * ad4.x + a1 * ad4.y + a2 * ad4.z + a3 * ad4.w;
            #pragma unroll
            for (int off = 16; off; off >>= 1) {
                ps += __shfl_down(ps, off, 32);
                pd += __shfl_down(pd, off, 32);
            }
            if (lane == 0) { als[gr] = ps; ald[gr] = pd; }
        }
        __syncthreads();
    }
}

// ---------------------------------------------------------------------------
// CSR build: histogram over dst, exclusive scan, scatter src ids per bucket.
// ---------------------------------------------------------------------------
__global__ __launch_bounds__(256) void hist_kernel(
    const int* __restrict__ edst, int* __restrict__ deg, int E)
{
    int k = blockIdx.x * blockDim.x + threadIdx.x;
    if (k < E) atomicAdd(&deg[edst[k]], 1);
}

__global__ __launch_bounds__(SB) void scan_block_kernel(
    const int* __restrict__ in, int* __restrict__ out, int* __restrict__ bsum, int n)
{
    __shared__ int sh[SB];
    const int tid = threadIdx.x;
    const int i = blockIdx.x * SB + tid;
    int v = (i < n) ? in[i] : 0;
    sh[tid] = v;
    __syncthreads();
    for (int off = 1; off < SB; off <<= 1) {
        int t = (tid >= off) ? sh[tid - off] : 0;
        __syncthreads();
        sh[tid] += t;
        __syncthreads();
    }
    if (i < n) out[i] = sh[tid] - v;          // exclusive
    if (tid == SB - 1) bsum[blockIdx.x] = sh[tid];
}

__global__ __launch_bounds__(SB) void scan_top_kernel(int* __restrict__ bsum, int nb)
{
    __shared__ int sh[SB];
    const int tid = threadIdx.x;
    int v = (tid < nb) ? bsum[tid] : 0;
    sh[tid] = v;
    __syncthreads();
    for (int off = 1; off < SB; off <<= 1) {
        int t = (tid >= off) ? sh[tid - off] : 0;
        __syncthreads();
        sh[tid] += t;
        __syncthreads();
    }
    if (tid < nb) bsum[tid] = sh[tid] - v;    // exclusive
}

__global__ __launch_bounds__(SB) void scan_add_kernel(
    int* __restrict__ rowptr, const int* __restrict__ bsum, int n, int E)
{
    int i = blockIdx.x * SB + threadIdx.x;
    if (i < n) rowptr[i] += bsum[blockIdx.x];
    if (i == 0) rowptr[n] = E;
}

__global__ __launch_bounds__(256) void csr_scatter_kernel(
    const int* __restrict__ esrc, const int* __restrict__ edst,
    const int* __restrict__ rowptr, int* __restrict__ cursor,
    int* __restrict__ esorted, int E)
{
    int k = blockIdx.x * blockDim.x + threadIdx.x;
    if (k >= E) return;
    int d = edst[k];
    int pos = rowptr[d] + atomicAdd(&cursor[d], 1);
    esorted[pos] = esrc[k];
}

// ---------------------------------------------------------------------------
// Fused GAT aggregation: per dst node (one 64-lane wave): softmax over
// incoming edges (+ implicit self-loop), weighted sum of h[src], bias, ReLU.
// ---------------------------------------------------------------------------
__global__ __launch_bounds__(256) void gat_aggregate_kernel(
    const int* __restrict__ rowptr, const int* __restrict__ esorted,
    const float* __restrict__ als, const float* __restrict__ ald,
    const float* __restrict__ H, const float* __restrict__ b,
    float* __restrict__ out, int n)
{
    const int wid  = (int)((blockIdx.x * 256u + threadIdx.x) >> 6);
    const int lane = threadIdx.x & 63;
    if (wid >= n) return;
    const int d = wid;
    const int start = rowptr[d], end = rowptr[d + 1];
    const int deg = end - start;
    const float ald_d = ald[d];

    float e_self = als[d] + ald_d;
    e_self = (e_self >= 0.f) ? e_self : 0.2f * e_self;

    float e_reg = -INFINITY;
    int src_reg = 0;
    if (lane < deg) {
        src_reg = esorted[start + lane];
        float t = als[src_reg] + ald_d;
        e_reg = (t >= 0.f) ? t : 0.2f * t;
    }
    float m = e_reg;
    for (int j = start + 64 + lane; j < end; j += 64) {
        float t = als[esorted[j]] + ald_d;
        t = (t >= 0.f) ? t : 0.2f * t;
        m = fmaxf(m, t);
    }
    #pragma unroll
    for (int off = 32; off; off >>= 1) m = fmaxf(m, __shfl_xor(m, off, 64));
    m = fmaxf(m, e_self);

    const int c = lane * 2;
    float accx = 0.f, accy = 0.f, denom = 0.f;
    const int dmin = deg < 64 ? deg : 64;
    for (int j = 0; j < dmin; ++j) {
        const float e = __shfl(e_reg, j, 64);
        const int   s = __shfl(src_reg, j, 64);
        const float w = expf(e - m);
        denom += w;
        const float2 hv = *(const float2*)&H[(size_t)s * FD + c];
        accx = fmaf(w, hv.x, accx);
        accy = fmaf(w, hv.y, accy);
    }
    for (int j = 64; j < deg; ++j) {           // rare overflow path
        const int s = esorted[start + j];
        float t = als[s] + ald_d;
        t = (t >= 0.f) ? t : 0.2f * t;
        const float w = expf(t - m);
        denom += w;
        const float2 hv = *(const float2*)&H[(size_t)s * FD + c];
        accx = fmaf(w, hv.x, accx);
        accy = fmaf(w, hv.y, accy);
    }
    {   // self loop
        const float w = expf(e_self - m);
        denom += w;
        const float2 hv = *(const float2*)&H[(size_t)d * FD + c];
        accx = fmaf(w, hv.x, accx);
        accy = fmaf(w, hv.y, accy);
    }
    const float inv = 1.f / denom;
    const float2 bb = *(const float2*)&b[c];
    float2 o;
    o.x = fmaxf(fmaf(accx, inv, bb.x), 0.f);
    o.y = fmaxf(fmaf(accy, inv, bb.y), 0.f);
    *(float2*)&out[(size_t)d * FD + c] = o;
}

// ---------------------------------------------------------------------------
// Mean-pool per graph (batch sorted ascending). One block per graph.
// ---------------------------------------------------------------------------
__global__ __launch_bounds__(128) void pool_mean_kernel(
    const float* __restrict__ H, const int* __restrict__ batch,
    float* __restrict__ pooled, int n)
{
    int g = blockIdx.x;
    int lo = 0, hi = n;
    while (lo < hi) { int mid = (lo + hi) >> 1; if (batch[mid] < g) lo = mid + 1; else hi = mid; }
    int start = lo;
    hi = n;
    while (lo < hi) { int mid = (lo + hi) >> 1; if (batch[mid] < g + 1) lo = mid + 1; else hi = mid; }
    int end = lo;
    int col = threadIdx.x;
    float acc = 0.f;
    for (int i = start; i < end; ++i) acc += H[(size_t)i * FD + col];
    float cnt = (float)(end - start);
    pooled[(size_t)g * FD + col] = acc / fmaxf(cnt, 1.f);
}

// logits = [bu | td] @ fc_W + fc_b ; log_softmax. One thread per graph.
__global__ __launch_bounds__(256) void fc_logsoftmax_kernel(
    const float* __restrict__ bu, const float* __restrict__ td,
    const float* __restrict__ Wf, const float* __restrict__ bf,
    float* __restrict__ out, int g)
{
    int gid = blockIdx.x * blockDim.x + threadIdx.x;
    if (gid >= g) return;
    float l0 = bf[0], l1 = bf[1], l2 = bf[2], l3 = bf[3];
    for (int k = 0; k < FD; ++k) {
        float v = bu[(size_t)gid * FD + k];
        l0 = fmaf(v, Wf[k * 4 + 0], l0);
        l1 = fmaf(v, Wf[k * 4 + 1], l1);
        l2 = fmaf(v, Wf[k * 4 + 2], l2);
        l3 = fmaf(v, Wf[k * 4 + 3], l3);
    }
    for (int k = 0; k < FD; ++k) {
        float v = td[(size_t)gid * FD + k];
        l0 = fmaf(v, Wf[(FD + k) * 4 + 0], l0);
        l1 = fmaf(v, Wf[(FD + k) * 4 + 1], l1);
        l2 = fmaf(v, Wf[(FD + k) * 4 + 2], l2);
        l3 = fmaf(v, Wf[(FD + k) * 4 + 3], l3);
    }
    float m = fmaxf(fmaxf(l0, l1), fmaxf(l2, l3));
    float ssum = expf(l0 - m) + expf(l1 - m) + expf(l2 - m) + expf(l3 - m);
    float ls = logf(ssum);
    out[(size_t)gid * 4 + 0] = l0 - m - ls;
    out[(size_t)gid * 4 + 1] = l1 - m - ls;
    out[(size_t)gid * 4 + 2] = l2 - m - ls;
    out[(size_t)gid * 4 + 3] = l3 - m - ls;
}

extern "C" void kernel_launch(void* const* d_in, const int* in_sizes, int n_in,
                              void* d_out, int out_size, void* d_ws, size_t ws_size,
                              hipStream_t stream)
{
    const float* x      = (const float*)d_in[0];
    const int*   td_ei  = (const int*)d_in[1];
    const int*   bu_ei  = (const int*)d_in[2];
    const int*   batch  = (const int*)d_in[3];
    const float* fc_W   = (const float*)d_in[20];
    const float* fc_b   = (const float*)d_in[21];

    const int N = in_sizes[0] / FD;
    const int E = in_sizes[1] / 2;
    const int G = out_size / 4;
    const int nb = (N + SB - 1) / SB;   // scan blocks (<=512 required)

    // workspace layout
    char* p = (char*)d_ws;
    float* bufA = (float*)p;  p += roundup256((size_t)N * FD * 4);
    float* bufB = (float*)p;  p += roundup256((size_t)N * FD * 4);
    float* als  = (float*)p;  p += roundup256((size_t)N * 4);
    float* ald  = (float*)p;  p += roundup256((size_t)N * 4);
    int* rowptr = (int*)p;    p += roundup256((size_t)(N + 1) * 4);
    int* esorted = (int*)p;   p += roundup256((size_t)E * 4);
    int* deg    = (int*)p;    p += roundup256((size_t)N * 4);
    int* bsum   = (int*)p;    p += roundup256((size_t)SB * 4);
    float* pooled_td = (float*)p; p += roundup256((size_t)G * FD * 4);
    float* pooled_bu = (float*)p; p += roundup256((size_t)G * FD * 4);

    const dim3 blk256(256);
    const dim3 gGemm((N + 63) / 64);
    const dim3 gAgg((N + 3) / 4);       // 4 waves (nodes) per block
    const dim3 gE((E + 255) / 256);

    auto build_csr = [&](const int* ei) {
        const int* esrc = ei;
        const int* edst = ei + E;
        hipMemsetAsync(deg, 0, (size_t)N * 4, stream);
        hist_kernel<<<gE, blk256, 0, stream>>>(edst, deg, E);
        scan_block_kernel<<<dim3(nb), dim3(SB), 0, stream>>>(deg, rowptr, bsum, N);
        scan_top_kernel<<<dim3(1), dim3(SB), 0, stream>>>(bsum, nb);
        scan_add_kernel<<<dim3(nb), dim3(SB), 0, stream>>>(rowptr, bsum, N, E);
        hipMemsetAsync(deg, 0, (size_t)N * 4, stream);   // reuse as cursor
        csr_scatter_kernel<<<gE, blk256, 0, stream>>>(esrc, edst, rowptr, deg, esorted, E);
    };

    auto run_layer = [&](const float* Xin, const float* W, const float* as_,
                         const float* ad_, const float* b_,
                         float* hbuf, float* obuf) {
        gemm_al_kernel<<<gGemm, blk256, 0, stream>>>(Xin, W, as_, ad_, hbuf, als, ald, N);
        gat_aggregate_kernel<<<gAgg, blk256, 0, stream>>>(rowptr, esorted, als, ald, hbuf, b_, obuf, N);
    };

    auto run_branch = [&](const int* ei, int base, float* pooled) {
        const float* W1  = (const float*)d_in[base + 0];
        const float* as1 = (const float*)d_in[base + 1];
        const float* ad1 = (const float*)d_in[base + 2];
        const float* b1  = (const float*)d_in[base + 3];
        const float* W2  = (const float*)d_in[base + 4];
        const float* as2 = (const float*)d_in[base + 5];
        const float* ad2 = (const float*)d_in[base + 6];
        const float* b2  = (const float*)d_in[base + 7];
        build_csr(ei);
        // layer 1: x -> bufA (h), aggregate -> bufB
        run_layer(x, W1, as1, ad1, b1, bufA, bufB);
        // layer 2: bufB -> bufA (h), aggregate -> bufB (GEMM consumed it already)
        run_layer(bufB, W2, as2, ad2, b2, bufA, bufB);
        pool_mean_kernel<<<dim3(G), dim3(128), 0, stream>>>(bufB, batch, pooled, N);
    };

    run_branch(td_ei, 4, pooled_td);
    run_branch(bu_ei, 12, pooled_bu);

    fc_logsoftmax_kernel<<<dim3((G + 255) / 256), blk256, 0, stream>>>(
        pooled_bu, pooled_td, fc_W, fc_b, (float*)d_out, G);
}

// Round 4
// 1157.364 us; speedup vs baseline: 10.8968x; 1.2384x over previous
//
#include <hip/hip_runtime.h>

#define FD 128
#define SB 512
#define XLPAD 132

static inline size_t roundup256(size_t x) { return (x + 255) & ~(size_t)255; }

// ---------------------------------------------------------------------------
// GEMM: H[nrows,128] = X[nrows,128] @ W[128,128], fused al_s = H.a_s, al_d = H.a_d
// 256 threads; thread (tr=tid>>4, tc=tid&15) computes rows tr*4..+3, cols tc*8..+7.
// X tile (64 rows) in padded LDS; W streamed from global (L2-resident).
// ---------------------------------------------------------------------------
__global__ __launch_bounds__(256) void gemm_al_kernel(
    const float* __restrict__ X, const float* __restrict__ W,
    const float* __restrict__ a_s, const float* __restrict__ a_d,
    float* __restrict__ H, float* __restrict__ als, float* __restrict__ ald,
    int nrows)
{
    __shared__ float Xl[64 * XLPAD];
    const int tid = threadIdx.x;
    const int tc = tid & 15;
    const int tr = tid >> 4;
    const int rb = blockIdx.x * 64;

    #pragma unroll
    for (int p = 0; p < 8; ++p) {
        int fidx = p * 256 + tid;
        int row = fidx >> 5;
        int c4 = (fidx & 31) << 2;
        float4 v = make_float4(0.f, 0.f, 0.f, 0.f);
        if (rb + row < nrows) v = *(const float4*)&X[(size_t)(rb + row) * FD + c4];
        *(float4*)&Xl[row * XLPAD + c4] = v;
    }

    const float4 asA = *(const float4*)&a_s[tc * 8];
    const float4 asB = *(const float4*)&a_s[tc * 8 + 4];
    const float4 adA = *(const float4*)&a_d[tc * 8];
    const float4 adB = *(const float4*)&a_d[tc * 8 + 4];

    float acc[4][8];
    #pragma unroll
    for (int i = 0; i < 4; ++i)
        #pragma unroll
        for (int j = 0; j < 8; ++j) acc[i][j] = 0.f;

    __syncthreads();

    const float* Wp = W + tc * 8;
    #pragma unroll 2
    for (int k = 0; k < FD; k += 2) {
        const float4 w0a = *(const float4*)&Wp[k * FD];
        const float4 w0b = *(const float4*)&Wp[k * FD + 4];
        const float4 w1a = *(const float4*)&Wp[(k + 1) * FD];
        const float4 w1b = *(const float4*)&Wp[(k + 1) * FD + 4];
        #pragma unroll
        for (int i = 0; i < 4; ++i) {
            const float2 xv = *(const float2*)&Xl[(tr * 4 + i) * XLPAD + k];
            acc[i][0] = fmaf(xv.x, w0a.x, acc[i][0]);
            acc[i][1] = fmaf(xv.x, w0a.y, acc[i][1]);
            acc[i][2] = fmaf(xv.x, w0a.z, acc[i][2]);
            acc[i][3] = fmaf(xv.x, w0a.w, acc[i][3]);
            acc[i][4] = fmaf(xv.x, w0b.x, acc[i][4]);
            acc[i][5] = fmaf(xv.x, w0b.y, acc[i][5]);
            acc[i][6] = fmaf(xv.x, w0b.z, acc[i][6]);
            acc[i][7] = fmaf(xv.x, w0b.w, acc[i][7]);
            acc[i][0] = fmaf(xv.y, w1a.x, acc[i][0]);
            acc[i][1] = fmaf(xv.y, w1a.y, acc[i][1]);
            acc[i][2] = fmaf(xv.y, w1a.z, acc[i][2]);
            acc[i][3] = fmaf(xv.y, w1a.w, acc[i][3]);
            acc[i][4] = fmaf(xv.y, w1b.x, acc[i][4]);
            acc[i][5] = fmaf(xv.y, w1b.y, acc[i][5]);
            acc[i][6] = fmaf(xv.y, w1b.z, acc[i][6]);
            acc[i][7] = fmaf(xv.y, w1b.w, acc[i][7]);
        }
    }

    #pragma unroll
    for (int i = 0; i < 4; ++i) {
        const int row = rb + tr * 4 + i;
        float ps = acc[i][0]*asA.x + acc[i][1]*asA.y + acc[i][2]*asA.z + acc[i][3]*asA.w
                 + acc[i][4]*asB.x + acc[i][5]*asB.y + acc[i][6]*asB.z + acc[i][7]*asB.w;
        float pd = acc[i][0]*adA.x + acc[i][1]*adA.y + acc[i][2]*adA.z + acc[i][3]*adA.w
                 + acc[i][4]*adB.x + acc[i][5]*adB.y + acc[i][6]*adB.z + acc[i][7]*adB.w;
        #pragma unroll
        for (int off = 8; off; off >>= 1) {
            ps += __shfl_down(ps, off, 16);
            pd += __shfl_down(pd, off, 16);
        }
        if (row < nrows) {
            *(float4*)&H[(size_t)row * FD + tc * 8]     = make_float4(acc[i][0], acc[i][1], acc[i][2], acc[i][3]);
            *(float4*)&H[(size_t)row * FD + tc * 8 + 4] = make_float4(acc[i][4], acc[i][5], acc[i][6], acc[i][7]);
            if (tc == 0) { als[row] = ps; ald[row] = pd; }
        }
    }
}

// ---------------------------------------------------------------------------
// CSR build: histogram over dst, exclusive scan, scatter src ids per bucket.
// ---------------------------------------------------------------------------
__global__ __launch_bounds__(256) void hist_kernel(
    const int* __restrict__ edst, int* __restrict__ deg, int E)
{
    int k = blockIdx.x * blockDim.x + threadIdx.x;
    if (k < E) atomicAdd(&deg[edst[k]], 1);
}

__global__ __launch_bounds__(SB) void scan_block_kernel(
    const int* __restrict__ in, int* __restrict__ out, int* __restrict__ bsum, int n)
{
    __shared__ int sh[SB];
    const int tid = threadIdx.x;
    const int i = blockIdx.x * SB + tid;
    int v = (i < n) ? in[i] : 0;
    sh[tid] = v;
    __syncthreads();
    for (int off = 1; off < SB; off <<= 1) {
        int t = (tid >= off) ? sh[tid - off] : 0;
        __syncthreads();
        sh[tid] += t;
        __syncthreads();
    }
    if (i < n) out[i] = sh[tid] - v;
    if (tid == SB - 1) bsum[blockIdx.x] = sh[tid];
}

__global__ __launch_bounds__(SB) void scan_top_kernel(int* __restrict__ bsum, int nb)
{
    __shared__ int sh[SB];
    const int tid = threadIdx.x;
    int v = (tid < nb) ? bsum[tid] : 0;
    sh[tid] = v;
    __syncthreads();
    for (int off = 1; off < SB; off <<= 1) {
        int t = (tid >= off) ? sh[tid - off] : 0;
        __syncthreads();
        sh[tid] += t;
        __syncthreads();
    }
    if (tid < nb) bsum[tid] = sh[tid] - v;
}

__global__ __launch_bounds__(SB) void scan_add_kernel(
    int* __restrict__ rowptr, const int* __restrict__ bsum, int n, int E)
{
    int i = blockIdx.x * SB + threadIdx.x;
    if (i < n) rowptr[i] += bsum[blockIdx.x];
    if (i == 0) rowptr[n] = E;
}

__global__ __launch_bounds__(256) void csr_scatter_kernel(
    const int* __restrict__ esrc, const int* __restrict__ edst,
    const int* __restrict__ rowptr, int* __restrict__ cursor,
    int* __restrict__ esorted, int E)
{
    int k = blockIdx.x * blockDim.x + threadIdx.x;
    if (k >= E) return;
    int d = edst[k];
    int pos = rowptr[d] + atomicAdd(&cursor[d], 1);
    esorted[pos] = esrc[k];
}

// ---------------------------------------------------------------------------
// Fused GAT aggregation. One 64-lane wave per dst node.
// ---------------------------------------------------------------------------
__global__ __launch_bounds__(256) void gat_aggregate_kernel(
    const int* __restrict__ rowptr, const int* __restrict__ esorted,
    const float* __restrict__ als, const float* __restrict__ ald,
    const float* __restrict__ H, const float* __restrict__ b,
    float* __restrict__ out, int n)
{
    const int wid  = (int)((blockIdx.x * 256u + threadIdx.x) >> 6);
    const int lane = threadIdx.x & 63;
    if (wid >= n) return;
    const int d = wid;
    const int start = rowptr[d], end = rowptr[d + 1];
    const int deg = end - start;
    const float ald_d = ald[d];
    const int c = lane * 2;

    const float2 hself = *(const float2*)&H[(size_t)d * FD + c];

    float e_self = als[d] + ald_d;
    e_self = (e_self >= 0.f) ? e_self : 0.2f * e_self;

    float e_reg = -INFINITY;
    int src_reg = 0;
    if (lane < deg) {
        src_reg = esorted[start + lane];
        float t = als[src_reg] + ald_d;
        e_reg = (t >= 0.f) ? t : 0.2f * t;
    }
    float m = e_reg;
    for (int j = start + 64 + lane; j < end; j += 64) {
        float t = als[esorted[j]] + ald_d;
        t = (t >= 0.f) ? t : 0.2f * t;
        m = fmaxf(m, t);
    }
    #pragma unroll
    for (int off = 32; off; off >>= 1) m = fmaxf(m, __shfl_xor(m, off, 64));
    m = fmaxf(m, e_self);

    const float w_self = __expf(e_self - m);
    const float w_reg  = __expf(e_reg - m);    // 0 for lanes >= deg (e=-inf)

    float dsum = w_reg;
    #pragma unroll
    for (int off = 32; off; off >>= 1) dsum += __shfl_xor(dsum, off, 64);
    float denom = dsum + w_self;

    float accx = w_self * hself.x;
    float accy = w_self * hself.y;

    const int dmin = deg < 64 ? deg : 64;
    int j = 0;
    for (; j + 3 < dmin; j += 4) {
        const int   s0 = __shfl(src_reg, j,     64);
        const int   s1 = __shfl(src_reg, j + 1, 64);
        const int   s2 = __shfl(src_reg, j + 2, 64);
        const int   s3 = __shfl(src_reg, j + 3, 64);
        const float w0 = __shfl(w_reg, j,     64);
        const float w1 = __shfl(w_reg, j + 1, 64);
        const float w2 = __shfl(w_reg, j + 2, 64);
        const float w3 = __shfl(w_reg, j + 3, 64);
        const float2 h0 = *(const float2*)&H[(size_t)s0 * FD + c];
        const float2 h1 = *(const float2*)&H[(size_t)s1 * FD + c];
        const float2 h2 = *(const float2*)&H[(size_t)s2 * FD + c];
        const float2 h3 = *(const float2*)&H[(size_t)s3 * FD + c];
        accx = fmaf(w0, h0.x, accx); accy = fmaf(w0, h0.y, accy);
        accx = fmaf(w1, h1.x, accx); accy = fmaf(w1, h1.y, accy);
        accx = fmaf(w2, h2.x, accx); accy = fmaf(w2, h2.y, accy);
        accx = fmaf(w3, h3.x, accx); accy = fmaf(w3, h3.y, accy);
    }
    for (; j < dmin; ++j) {
        const int   s = __shfl(src_reg, j, 64);
        const float w = __shfl(w_reg, j, 64);
        const float2 hv = *(const float2*)&H[(size_t)s * FD + c];
        accx = fmaf(w, hv.x, accx); accy = fmaf(w, hv.y, accy);
    }
    for (int jj = 64; jj < deg; ++jj) {         // rare deep-degree tail
        const int s = esorted[start + jj];
        float t = als[s] + ald_d;
        t = (t >= 0.f) ? t : 0.2f * t;
        const float w = __expf(t - m);
        denom += w;
        const float2 hv = *(const float2*)&H[(size_t)s * FD + c];
        accx = fmaf(w, hv.x, accx); accy = fmaf(w, hv.y, accy);
    }
    const float inv = 1.f / denom;
    const float2 bb = *(const float2*)&b[c];
    float2 o;
    o.x = fmaxf(fmaf(accx, inv, bb.x), 0.f);
    o.y = fmaxf(fmaf(accy, inv, bb.y), 0.f);
    *(float2*)&out[(size_t)d * FD + c] = o;
}

// ---------------------------------------------------------------------------
// Mean-pool per graph (batch sorted). One block (512 thr, 4-way rows) per graph.
// ---------------------------------------------------------------------------
__global__ __launch_bounds__(512) void pool_mean_kernel(
    const float* __restrict__ H, const int* __restrict__ batch,
    float* __restrict__ pooled, int n)
{
    __shared__ float sh[3][FD];
    int g = blockIdx.x;
    int lo = 0, hi = n;
    while (lo < hi) { int mid = (lo + hi) >> 1; if (batch[mid] < g) lo = mid + 1; else hi = mid; }
    int start = lo;
    hi = n;
    while (lo < hi) { int mid = (lo + hi) >> 1; if (batch[mid] < g + 1) lo = mid + 1; else hi = mid; }
    int end = lo;
    int col = threadIdx.x & 127;
    int q   = threadIdx.x >> 7;
    float acc = 0.f;
    for (int i = start + q; i < end; i += 4) acc += H[(size_t)i * FD + col];
    if (q) sh[q - 1][col] = acc;
    __syncthreads();
    if (!q) {
        float tot = acc + sh[0][col] + sh[1][col] + sh[2][col];
        float cnt = (float)(end - start);
        pooled[(size_t)g * FD + col] = tot / fmaxf(cnt, 1.f);
    }
}

// logits = [bu | td] @ fc_W + fc_b ; log_softmax. One wave per graph.
__global__ __launch_bounds__(256) void fc_logsoftmax_kernel(
    const float* __restrict__ bu, const float* __restrict__ td,
    const float* __restrict__ Wf, const float* __restrict__ bf,
    float* __restrict__ out, int g)
{
    const int wid  = (int)((blockIdx.x * 256u + threadIdx.x) >> 6);
    const int lane = threadIdx.x & 63;
    if (wid >= g) return;
    const float f0 = bu[(size_t)wid * FD + lane];
    const float f1 = bu[(size_t)wid * FD + 64 + lane];
    const float f2 = td[(size_t)wid * FD + lane];
    const float f3 = td[(size_t)wid * FD + 64 + lane];
    const float4 w0 = *(const float4*)&Wf[lane * 4];
    const float4 w1 = *(const float4*)&Wf[(64 + lane) * 4];
    const float4 w2 = *(const float4*)&Wf[(128 + lane) * 4];
    const float4 w3 = *(const float4*)&Wf[(192 + lane) * 4];
    float l0 = f0 * w0.x + f1 * w1.x + f2 * w2.x + f3 * w3.x;
    float l1 = f0 * w0.y + f1 * w1.y + f2 * w2.y + f3 * w3.y;
    float l2 = f0 * w0.z + f1 * w1.z + f2 * w2.z + f3 * w3.z;
    float l3 = f0 * w0.w + f1 * w1.w + f2 * w2.w + f3 * w3.w;
    #pragma unroll
    for (int off = 32; off; off >>= 1) {
        l0 += __shfl_xor(l0, off, 64);
        l1 += __shfl_xor(l1, off, 64);
        l2 += __shfl_xor(l2, off, 64);
        l3 += __shfl_xor(l3, off, 64);
    }
    if (lane == 0) {
        l0 += bf[0]; l1 += bf[1]; l2 += bf[2]; l3 += bf[3];
        float m = fmaxf(fmaxf(l0, l1), fmaxf(l2, l3));
        float ssum = expf(l0 - m) + expf(l1 - m) + expf(l2 - m) + expf(l3 - m);
        float ls = logf(ssum);
        out[(size_t)wid * 4 + 0] = l0 - m - ls;
        out[(size_t)wid * 4 + 1] = l1 - m - ls;
        out[(size_t)wid * 4 + 2] = l2 - m - ls;
        out[(size_t)wid * 4 + 3] = l3 - m - ls;
    }
}

extern "C" void kernel_launch(void* const* d_in, const int* in_sizes, int n_in,
                              void* d_out, int out_size, void* d_ws, size_t ws_size,
                              hipStream_t stream)
{
    const float* x      = (const float*)d_in[0];
    const int*   td_ei  = (const int*)d_in[1];
    const int*   bu_ei  = (const int*)d_in[2];
    const int*   batch  = (const int*)d_in[3];
    const float* fc_W   = (const float*)d_in[20];
    const float* fc_b   = (const float*)d_in[21];

    const int N = in_sizes[0] / FD;
    const int E = in_sizes[1] / 2;
    const int G = out_size / 4;
    const int nb = (N + SB - 1) / SB;

    char* p = (char*)d_ws;
    float* bufA = (float*)p;  p += roundup256((size_t)N * FD * 4);
    float* bufB = (float*)p;  p += roundup256((size_t)N * FD * 4);
    float* als  = (float*)p;  p += roundup256((size_t)N * 4);
    float* ald  = (float*)p;  p += roundup256((size_t)N * 4);
    int* rowptr = (int*)p;    p += roundup256((size_t)(N + 1) * 4);
    int* esorted = (int*)p;   p += roundup256((size_t)E * 4);
    int* deg    = (int*)p;    p += roundup256((size_t)N * 4);
    int* bsum   = (int*)p;    p += roundup256((size_t)SB * 4);
    float* pooled_td = (float*)p; p += roundup256((size_t)G * FD * 4);
    float* pooled_bu = (float*)p; p += roundup256((size_t)G * FD * 4);

    const dim3 blk256(256);
    const dim3 gGemm((N + 63) / 64);
    const dim3 gAgg((N + 3) / 4);
    const dim3 gE((E + 255) / 256);

    auto build_csr = [&](const int* ei) {
        const int* esrc = ei;
        const int* edst = ei + E;
        hipMemsetAsync(deg, 0, (size_t)N * 4, stream);
        hist_kernel<<<gE, blk256, 0, stream>>>(edst, deg, E);
        scan_block_kernel<<<dim3(nb), dim3(SB), 0, stream>>>(deg, rowptr, bsum, N);
        scan_top_kernel<<<dim3(1), dim3(SB), 0, stream>>>(bsum, nb);
        scan_add_kernel<<<dim3(nb), dim3(SB), 0, stream>>>(rowptr, bsum, N, E);
        hipMemsetAsync(deg, 0, (size_t)N * 4, stream);
        csr_scatter_kernel<<<gE, blk256, 0, stream>>>(esrc, edst, rowptr, deg, esorted, E);
    };

    auto run_layer = [&](const float* Xin, const float* W, const float* as_,
                         const float* ad_, const float* b_,
                         float* hbuf, float* obuf) {
        gemm_al_kernel<<<gGemm, blk256, 0, stream>>>(Xin, W, as_, ad_, hbuf, als, ald, N);
        gat_aggregate_kernel<<<gAgg, blk256, 0, stream>>>(rowptr, esorted, als, ald, hbuf, b_, obuf, N);
    };

    auto run_branch = [&](const int* ei, int base, float* pooled) {
        const float* W1  = (const float*)d_in[base + 0];
        const float* as1 = (const float*)d_in[base + 1];
        const float* ad1 = (const float*)d_in[base + 2];
        const float* b1  = (const float*)d_in[base + 3];
        const float* W2  = (const float*)d_in[base + 4];
        const float* as2 = (const float*)d_in[base + 5];
        const float* ad2 = (const float*)d_in[base + 6];
        const float* b2  = (const float*)d_in[base + 7];
        build_csr(ei);
        run_layer(x, W1, as1, ad1, b1, bufA, bufB);
        run_layer(bufB, W2, as2, ad2, b2, bufA, bufB);
        pool_mean_kernel<<<dim3(G), dim3(512), 0, stream>>>(bufB, batch, pooled, N);
    };

    run_branch(td_ei, 4, pooled_td);
    run_branch(bu_ei, 12, pooled_bu);

    // 4 waves (graphs) per 256-thread block -> (G+3)/4 blocks  [R3 bug: was (G+63)/64]
    fc_logsoftmax_kernel<<<dim3((G + 3) / 4), blk256, 0, stream>>>(
        pooled_bu, pooled_td, fc_W, fc_b, (float*)d_out, G);
}

// Round 5
// 1014.976 us; speedup vs baseline: 12.4255x; 1.1403x over previous
//
#include <hip/hip_runtime.h>

#define FD 128
#define SB 512
#define XLPAD 132

static inline size_t roundup256(size_t x) { return (x + 255) & ~(size_t)255; }

// ---------------------------------------------------------------------------
// GEMM: H[nrows,128] = X[nrows,128] @ W[128,128], fused al_s = H.a_s, al_d = H.a_d
// 256 threads; thread (tr=tid>>4, tc=tid&15) computes rows tr*4..+3, cols tc*8..+7.
// X tile (64 rows) in padded LDS; W streamed from global (L2-resident).
// ---------------------------------------------------------------------------
__global__ __launch_bounds__(256) void gemm_al_kernel(
    const float* __restrict__ X, const float* __restrict__ W,
    const float* __restrict__ a_s, const float* __restrict__ a_d,
    float* __restrict__ H, float* __restrict__ als, float* __restrict__ ald,
    int nrows)
{
    __shared__ float Xl[64 * XLPAD];
    const int tid = threadIdx.x;
    const int tc = tid & 15;
    const int tr = tid >> 4;
    const int rb = blockIdx.x * 64;

    #pragma unroll
    for (int p = 0; p < 8; ++p) {
        int fidx = p * 256 + tid;
        int row = fidx >> 5;
        int c4 = (fidx & 31) << 2;
        float4 v = make_float4(0.f, 0.f, 0.f, 0.f);
        if (rb + row < nrows) v = *(const float4*)&X[(size_t)(rb + row) * FD + c4];
        *(float4*)&Xl[row * XLPAD + c4] = v;
    }

    const float4 asA = *(const float4*)&a_s[tc * 8];
    const float4 asB = *(const float4*)&a_s[tc * 8 + 4];
    const float4 adA = *(const float4*)&a_d[tc * 8];
    const float4 adB = *(const float4*)&a_d[tc * 8 + 4];

    float acc[4][8];
    #pragma unroll
    for (int i = 0; i < 4; ++i)
        #pragma unroll
        for (int j = 0; j < 8; ++j) acc[i][j] = 0.f;

    __syncthreads();

    const float* Wp = W + tc * 8;
    #pragma unroll 2
    for (int k = 0; k < FD; k += 2) {
        const float4 w0a = *(const float4*)&Wp[k * FD];
        const float4 w0b = *(const float4*)&Wp[k * FD + 4];
        const float4 w1a = *(const float4*)&Wp[(k + 1) * FD];
        const float4 w1b = *(const float4*)&Wp[(k + 1) * FD + 4];
        #pragma unroll
        for (int i = 0; i < 4; ++i) {
            const float2 xv = *(const float2*)&Xl[(tr * 4 + i) * XLPAD + k];
            acc[i][0] = fmaf(xv.x, w0a.x, acc[i][0]);
            acc[i][1] = fmaf(xv.x, w0a.y, acc[i][1]);
            acc[i][2] = fmaf(xv.x, w0a.z, acc[i][2]);
            acc[i][3] = fmaf(xv.x, w0a.w, acc[i][3]);
            acc[i][4] = fmaf(xv.x, w0b.x, acc[i][4]);
            acc[i][5] = fmaf(xv.x, w0b.y, acc[i][5]);
            acc[i][6] = fmaf(xv.x, w0b.z, acc[i][6]);
            acc[i][7] = fmaf(xv.x, w0b.w, acc[i][7]);
            acc[i][0] = fmaf(xv.y, w1a.x, acc[i][0]);
            acc[i][1] = fmaf(xv.y, w1a.y, acc[i][1]);
            acc[i][2] = fmaf(xv.y, w1a.z, acc[i][2]);
            acc[i][3] = fmaf(xv.y, w1a.w, acc[i][3]);
            acc[i][4] = fmaf(xv.y, w1b.x, acc[i][4]);
            acc[i][5] = fmaf(xv.y, w1b.y, acc[i][5]);
            acc[i][6] = fmaf(xv.y, w1b.z, acc[i][6]);
            acc[i][7] = fmaf(xv.y, w1b.w, acc[i][7]);
        }
    }

    #pragma unroll
    for (int i = 0; i < 4; ++i) {
        const int row = rb + tr * 4 + i;
        float ps = acc[i][0]*asA.x + acc[i][1]*asA.y + acc[i][2]*asA.z + acc[i][3]*asA.w
                 + acc[i][4]*asB.x + acc[i][5]*asB.y + acc[i][6]*asB.z + acc[i][7]*asB.w;
        float pd = acc[i][0]*adA.x + acc[i][1]*adA.y + acc[i][2]*adA.z + acc[i][3]*adA.w
                 + acc[i][4]*adB.x + acc[i][5]*adB.y + acc[i][6]*adB.z + acc[i][7]*adB.w;
        #pragma unroll
        for (int off = 8; off; off >>= 1) {
            ps += __shfl_down(ps, off, 16);
            pd += __shfl_down(pd, off, 16);
        }
        if (row < nrows) {
            *(float4*)&H[(size_t)row * FD + tc * 8]     = make_float4(acc[i][0], acc[i][1], acc[i][2], acc[i][3]);
            *(float4*)&H[(size_t)row * FD + tc * 8 + 4] = make_float4(acc[i][4], acc[i][5], acc[i][6], acc[i][7]);
            if (tc == 0) { als[row] = ps; ald[row] = pd; }
        }
    }
}

// ---------------------------------------------------------------------------
// CSR build: histogram+rank over dst, exclusive scan, atomic-free scatter.
// ---------------------------------------------------------------------------
__global__ __launch_bounds__(256) void hist_rank_kernel(
    const int* __restrict__ edst, int* __restrict__ deg, int* __restrict__ rank, int E)
{
    int k = blockIdx.x * blockDim.x + threadIdx.x;
    if (k < E) rank[k] = atomicAdd(&deg[edst[k]], 1);
}

__global__ __launch_bounds__(SB) void scan_block_kernel(
    const int* __restrict__ in, int* __restrict__ out, int* __restrict__ bsum, int n)
{
    __shared__ int sh[SB];
    const int tid = threadIdx.x;
    const int i = blockIdx.x * SB + tid;
    int v = (i < n) ? in[i] : 0;
    sh[tid] = v;
    __syncthreads();
    for (int off = 1; off < SB; off <<= 1) {
        int t = (tid >= off) ? sh[tid - off] : 0;
        __syncthreads();
        sh[tid] += t;
        __syncthreads();
    }
    if (i < n) out[i] = sh[tid] - v;
    if (tid == SB - 1) bsum[blockIdx.x] = sh[tid];
}

__global__ __launch_bounds__(SB) void scan_top_kernel(int* __restrict__ bsum, int nb)
{
    __shared__ int sh[SB];
    const int tid = threadIdx.x;
    int v = (tid < nb) ? bsum[tid] : 0;
    sh[tid] = v;
    __syncthreads();
    for (int off = 1; off < SB; off <<= 1) {
        int t = (tid >= off) ? sh[tid - off] : 0;
        __syncthreads();
        sh[tid] += t;
        __syncthreads();
    }
    if (tid < nb) bsum[tid] = sh[tid] - v;
}

__global__ __launch_bounds__(SB) void scan_add_kernel(
    int* __restrict__ rowptr, const int* __restrict__ bsum, int n, int E)
{
    int i = blockIdx.x * SB + threadIdx.x;
    if (i < n) rowptr[i] += bsum[blockIdx.x];
    if (i == 0) rowptr[n] = E;
}

__global__ __launch_bounds__(256) void csr_scatter_kernel(
    const int* __restrict__ esrc, const int* __restrict__ edst,
    const int* __restrict__ rowptr, const int* __restrict__ rank,
    int* __restrict__ esorted, int E)
{
    int k = blockIdx.x * blockDim.x + threadIdx.x;
    if (k >= E) return;
    esorted[rowptr[edst[k]] + rank[k]] = esrc[k];
}

// ---------------------------------------------------------------------------
// Fused GAT aggregation. One node per 32-lane half-wave; lane owns 4 cols
// (float4 gathers, 16B/lane). Softmax staged in registers (<=32 edges fast path).
// ---------------------------------------------------------------------------
__global__ __launch_bounds__(256) void gat_aggregate_kernel(
    const int* __restrict__ rowptr, const int* __restrict__ esorted,
    const float* __restrict__ als, const float* __restrict__ ald,
    const float* __restrict__ H, const float* __restrict__ b,
    float* __restrict__ out, int n)
{
    const int d    = (int)((blockIdx.x * 256u + threadIdx.x) >> 5);
    const int lane = threadIdx.x & 31;
    if (d >= n) return;
    const int start = rowptr[d], end = rowptr[d + 1];
    const int deg = end - start;
    const float ald_d = ald[d];
    const int c = lane * 4;

    const float4 hself = *(const float4*)&H[(size_t)d * FD + c];

    float e_self = als[d] + ald_d;
    e_self = (e_self >= 0.f) ? e_self : 0.2f * e_self;

    float e_reg = -INFINITY;
    int src_reg = 0;
    if (lane < deg) {
        src_reg = esorted[start + lane];
        float t = als[src_reg] + ald_d;
        e_reg = (t >= 0.f) ? t : 0.2f * t;
    }
    float m = e_reg;
    for (int j = start + 32 + lane; j < end; j += 32) {
        float t = als[esorted[j]] + ald_d;
        t = (t >= 0.f) ? t : 0.2f * t;
        m = fmaxf(m, t);
    }
    #pragma unroll
    for (int off = 16; off; off >>= 1) m = fmaxf(m, __shfl_xor(m, off, 32));
    m = fmaxf(m, e_self);

    const float w_self = __expf(e_self - m);
    const float w_reg  = __expf(e_reg - m);    // 0 for lanes >= deg (e=-inf)

    float dsum = w_reg;
    #pragma unroll
    for (int off = 16; off; off >>= 1) dsum += __shfl_xor(dsum, off, 32);
    float denom = dsum + w_self;

    float ax = w_self * hself.x;
    float ay = w_self * hself.y;
    float az = w_self * hself.z;
    float aw = w_self * hself.w;

    const int dmin = deg < 32 ? deg : 32;
    int j = 0;
    for (; j + 3 < dmin; j += 4) {
        const int   s0 = __shfl(src_reg, j,     32);
        const int   s1 = __shfl(src_reg, j + 1, 32);
        const int   s2 = __shfl(src_reg, j + 2, 32);
        const int   s3 = __shfl(src_reg, j + 3, 32);
        const float w0 = __shfl(w_reg, j,     32);
        const float w1 = __shfl(w_reg, j + 1, 32);
        const float w2 = __shfl(w_reg, j + 2, 32);
        const float w3 = __shfl(w_reg, j + 3, 32);
        const float4 h0 = *(const float4*)&H[(size_t)s0 * FD + c];
        const float4 h1 = *(const float4*)&H[(size_t)s1 * FD + c];
        const float4 h2 = *(const float4*)&H[(size_t)s2 * FD + c];
        const float4 h3 = *(const float4*)&H[(size_t)s3 * FD + c];
        ax = fmaf(w0, h0.x, ax); ay = fmaf(w0, h0.y, ay); az = fmaf(w0, h0.z, az); aw = fmaf(w0, h0.w, aw);
        ax = fmaf(w1, h1.x, ax); ay = fmaf(w1, h1.y, ay); az = fmaf(w1, h1.z, az); aw = fmaf(w1, h1.w, aw);
        ax = fmaf(w2, h2.x, ax); ay = fmaf(w2, h2.y, ay); az = fmaf(w2, h2.z, az); aw = fmaf(w2, h2.w, aw);
        ax = fmaf(w3, h3.x, ax); ay = fmaf(w3, h3.y, ay); az = fmaf(w3, h3.z, az); aw = fmaf(w3, h3.w, aw);
    }
    for (; j < dmin; ++j) {
        const int   s = __shfl(src_reg, j, 32);
        const float w = __shfl(w_reg, j, 32);
        const float4 hv = *(const float4*)&H[(size_t)s * FD + c];
        ax = fmaf(w, hv.x, ax); ay = fmaf(w, hv.y, ay); az = fmaf(w, hv.z, az); aw = fmaf(w, hv.w, aw);
    }
    for (int jj = 32; jj < deg; ++jj) {         // tail (deg > 32), all lanes same edge
        const int s = esorted[start + jj];
        float t = als[s] + ald_d;
        t = (t >= 0.f) ? t : 0.2f * t;
        const float w = __expf(t - m);
        denom += w;
        const float4 hv = *(const float4*)&H[(size_t)s * FD + c];
        ax = fmaf(w, hv.x, ax); ay = fmaf(w, hv.y, ay); az = fmaf(w, hv.z, az); aw = fmaf(w, hv.w, aw);
    }
    const float inv = 1.f / denom;
    const float4 bb = *(const float4*)&b[c];
    float4 o;
    o.x = fmaxf(fmaf(ax, inv, bb.x), 0.f);
    o.y = fmaxf(fmaf(ay, inv, bb.y), 0.f);
    o.z = fmaxf(fmaf(az, inv, bb.z), 0.f);
    o.w = fmaxf(fmaf(aw, inv, bb.w), 0.f);
    *(float4*)&out[(size_t)d * FD + c] = o;
}

// ---------------------------------------------------------------------------
// Mean-pool per graph (batch sorted). One block (512 thr, 4-way rows) per graph.
// ---------------------------------------------------------------------------
__global__ __launch_bounds__(512) void pool_mean_kernel(
    const float* __restrict__ H, const int* __restrict__ batch,
    float* __restrict__ pooled, int n)
{
    __shared__ float sh[3][FD];
    int g = blockIdx.x;
    int lo = 0, hi = n;
    while (lo < hi) { int mid = (lo + hi) >> 1; if (batch[mid] < g) lo = mid + 1; else hi = mid; }
    int start = lo;
    hi = n;
    while (lo < hi) { int mid = (lo + hi) >> 1; if (batch[mid] < g + 1) lo = mid + 1; else hi = mid; }
    int end = lo;
    int col = threadIdx.x & 127;
    int q   = threadIdx.x >> 7;
    float acc = 0.f;
    for (int i = start + q; i < end; i += 4) acc += H[(size_t)i * FD + col];
    if (q) sh[q - 1][col] = acc;
    __syncthreads();
    if (!q) {
        float tot = acc + sh[0][col] + sh[1][col] + sh[2][col];
        float cnt = (float)(end - start);
        pooled[(size_t)g * FD + col] = tot / fmaxf(cnt, 1.f);
    }
}

// logits = [bu | td] @ fc_W + fc_b ; log_softmax. One wave per graph.
__global__ __launch_bounds__(256) void fc_logsoftmax_kernel(
    const float* __restrict__ bu, const float* __restrict__ td,
    const float* __restrict__ Wf, const float* __restrict__ bf,
    float* __restrict__ out, int g)
{
    const int wid  = (int)((blockIdx.x * 256u + threadIdx.x) >> 6);
    const int lane = threadIdx.x & 63;
    if (wid >= g) return;
    const float f0 = bu[(size_t)wid * FD + lane];
    const float f1 = bu[(size_t)wid * FD + 64 + lane];
    const float f2 = td[(size_t)wid * FD + lane];
    const float f3 = td[(size_t)wid * FD + 64 + lane];
    const float4 w0 = *(const float4*)&Wf[lane * 4];
    const float4 w1 = *(const float4*)&Wf[(64 + lane) * 4];
    const float4 w2 = *(const float4*)&Wf[(128 + lane) * 4];
    const float4 w3 = *(const float4*)&Wf[(192 + lane) * 4];
    float l0 = f0 * w0.x + f1 * w1.x + f2 * w2.x + f3 * w3.x;
    float l1 = f0 * w0.y + f1 * w1.y + f2 * w2.y + f3 * w3.y;
    float l2 = f0 * w0.z + f1 * w1.z + f2 * w2.z + f3 * w3.z;
    float l3 = f0 * w0.w + f1 * w1.w + f2 * w2.w + f3 * w3.w;
    #pragma unroll
    for (int off = 32; off; off >>= 1) {
        l0 += __shfl_xor(l0, off, 64);
        l1 += __shfl_xor(l1, off, 64);
        l2 += __shfl_xor(l2, off, 64);
        l3 += __shfl_xor(l3, off, 64);
    }
    if (lane == 0) {
        l0 += bf[0]; l1 += bf[1]; l2 += bf[2]; l3 += bf[3];
        float m = fmaxf(fmaxf(l0, l1), fmaxf(l2, l3));
        float ssum = expf(l0 - m) + expf(l1 - m) + expf(l2 - m) + expf(l3 - m);
        float ls = logf(ssum);
        out[(size_t)wid * 4 + 0] = l0 - m - ls;
        out[(size_t)wid * 4 + 1] = l1 - m - ls;
        out[(size_t)wid * 4 + 2] = l2 - m - ls;
        out[(size_t)wid * 4 + 3] = l3 - m - ls;
    }
}

extern "C" void kernel_launch(void* const* d_in, const int* in_sizes, int n_in,
                              void* d_out, int out_size, void* d_ws, size_t ws_size,
                              hipStream_t stream)
{
    const float* x      = (const float*)d_in[0];
    const int*   td_ei  = (const int*)d_in[1];
    const int*   bu_ei  = (const int*)d_in[2];
    const int*   batch  = (const int*)d_in[3];
    const float* fc_W   = (const float*)d_in[20];
    const float* fc_b   = (const float*)d_in[21];

    const int N = in_sizes[0] / FD;
    const int E = in_sizes[1] / 2;
    const int G = out_size / 4;
    const int nb = (N + SB - 1) / SB;

    char* p = (char*)d_ws;
    float* bufA = (float*)p;  p += roundup256((size_t)N * FD * 4);
    float* bufB = (float*)p;  p += roundup256((size_t)N * FD * 4);
    float* als  = (float*)p;  p += roundup256((size_t)N * 4);
    float* ald  = (float*)p;  p += roundup256((size_t)N * 4);
    int* rowptr = (int*)p;    p += roundup256((size_t)(N + 1) * 4);
    int* esorted = (int*)p;   p += roundup256((size_t)E * 4);
    int* erank  = (int*)p;    p += roundup256((size_t)E * 4);
    int* deg    = (int*)p;    p += roundup256((size_t)N * 4);
    int* bsum   = (int*)p;    p += roundup256((size_t)SB * 4);
    float* pooled_td = (float*)p; p += roundup256((size_t)G * FD * 4);
    float* pooled_bu = (float*)p; p += roundup256((size_t)G * FD * 4);

    const dim3 blk256(256);
    const dim3 gGemm((N + 63) / 64);
    const dim3 gAgg((N + 7) / 8);       // 8 nodes (half-waves) per 256-thread block
    const dim3 gE((E + 255) / 256);

    auto build_csr = [&](const int* ei) {
        const int* esrc = ei;
        const int* edst = ei + E;
        hipMemsetAsync(deg, 0, (size_t)N * 4, stream);
        hist_rank_kernel<<<gE, blk256, 0, stream>>>(edst, deg, erank, E);
        scan_block_kernel<<<dim3(nb), dim3(SB), 0, stream>>>(deg, rowptr, bsum, N);
        scan_top_kernel<<<dim3(1), dim3(SB), 0, stream>>>(bsum, nb);
        scan_add_kernel<<<dim3(nb), dim3(SB), 0, stream>>>(rowptr, bsum, N, E);
        csr_scatter_kernel<<<gE, blk256, 0, stream>>>(esrc, edst, rowptr, erank, esorted, E);
    };

    auto run_layer = [&](const float* Xin, const float* W, const float* as_,
                         const float* ad_, const float* b_,
                         float* hbuf, float* obuf) {
        gemm_al_kernel<<<gGemm, blk256, 0, stream>>>(Xin, W, as_, ad_, hbuf, als, ald, N);
        gat_aggregate_kernel<<<gAgg, blk256, 0, stream>>>(rowptr, esorted, als, ald, hbuf, b_, obuf, N);
    };

    auto run_branch = [&](const int* ei, int base, float* pooled) {
        const float* W1  = (const float*)d_in[base + 0];
        const float* as1 = (const float*)d_in[base + 1];
        const float* ad1 = (const float*)d_in[base + 2];
        const float* b1  = (const float*)d_in[base + 3];
        const float* W2  = (const float*)d_in[base + 4];
        const float* as2 = (const float*)d_in[base + 5];
        const float* ad2 = (const float*)d_in[base + 6];
        const float* b2  = (const float*)d_in[base + 7];
        build_csr(ei);
        run_layer(x, W1, as1, ad1, b1, bufA, bufB);
        run_layer(bufB, W2, as2, ad2, b2, bufA, bufB);
        pool_mean_kernel<<<dim3(G), dim3(512), 0, stream>>>(bufB, batch, pooled, N);
    };

    run_branch(td_ei, 4, pooled_td);
    run_branch(bu_ei, 12, pooled_bu);

    // 4 waves (graphs) per 256-thread block
    fc_logsoftmax_kernel<<<dim3((G + 3) / 4), blk256, 0, stream>>>(
        pooled_bu, pooled_td, fc_W, fc_b, (float*)d_out, G);
}

// Round 6
// 782.798 us; speedup vs baseline: 16.1109x; 1.2966x over previous
//
#include <hip/hip_runtime.h>

#define FD 128
#define SB 512
#define XLPAD 132

static inline size_t roundup256(size_t x) { return (x + 255) & ~(size_t)255; }

// float -> bf16 with round-to-nearest-even
__device__ __forceinline__ unsigned short f2bf(float f) {
    unsigned u = __float_as_uint(f);
    u += 0x7FFFu + ((u >> 16) & 1u);
    return (unsigned short)(u >> 16);
}

// ---------------------------------------------------------------------------
// GEMM: h = X[nrows,128] @ W[128,128]; writes h as bf16 (H16) + al_s, al_d.
// f32 h is never materialized: only the aggregate consumes h.
// 256 threads; thread (tr,tc) computes rows tr*4..+3, cols tc*8..+7.
// ---------------------------------------------------------------------------
__global__ __launch_bounds__(256) void gemm_al_kernel(
    const float* __restrict__ X, const float* __restrict__ W,
    const float* __restrict__ a_s, const float* __restrict__ a_d,
    unsigned short* __restrict__ H16, float* __restrict__ als, float* __restrict__ ald,
    int nrows)
{
    __shared__ float Xl[64 * XLPAD];
    const int tid = threadIdx.x;
    const int tc = tid & 15;
    const int tr = tid >> 4;
    const int rb = blockIdx.x * 64;

    #pragma unroll
    for (int p = 0; p < 8; ++p) {
        int fidx = p * 256 + tid;
        int row = fidx >> 5;
        int c4 = (fidx & 31) << 2;
        float4 v = make_float4(0.f, 0.f, 0.f, 0.f);
        if (rb + row < nrows) v = *(const float4*)&X[(size_t)(rb + row) * FD + c4];
        *(float4*)&Xl[row * XLPAD + c4] = v;
    }

    const float4 asA = *(const float4*)&a_s[tc * 8];
    const float4 asB = *(const float4*)&a_s[tc * 8 + 4];
    const float4 adA = *(const float4*)&a_d[tc * 8];
    const float4 adB = *(const float4*)&a_d[tc * 8 + 4];

    float acc[4][8];
    #pragma unroll
    for (int i = 0; i < 4; ++i)
        #pragma unroll
        for (int j = 0; j < 8; ++j) acc[i][j] = 0.f;

    __syncthreads();

    const float* Wp = W + tc * 8;
    #pragma unroll 2
    for (int k = 0; k < FD; k += 2) {
        const float4 w0a = *(const float4*)&Wp[k * FD];
        const float4 w0b = *(const float4*)&Wp[k * FD + 4];
        const float4 w1a = *(const float4*)&Wp[(k + 1) * FD];
        const float4 w1b = *(const float4*)&Wp[(k + 1) * FD + 4];
        #pragma unroll
        for (int i = 0; i < 4; ++i) {
            const float2 xv = *(const float2*)&Xl[(tr * 4 + i) * XLPAD + k];
            acc[i][0] = fmaf(xv.x, w0a.x, acc[i][0]);
            acc[i][1] = fmaf(xv.x, w0a.y, acc[i][1]);
            acc[i][2] = fmaf(xv.x, w0a.z, acc[i][2]);
            acc[i][3] = fmaf(xv.x, w0a.w, acc[i][3]);
            acc[i][4] = fmaf(xv.x, w0b.x, acc[i][4]);
            acc[i][5] = fmaf(xv.x, w0b.y, acc[i][5]);
            acc[i][6] = fmaf(xv.x, w0b.z, acc[i][6]);
            acc[i][7] = fmaf(xv.x, w0b.w, acc[i][7]);
            acc[i][0] = fmaf(xv.y, w1a.x, acc[i][0]);
            acc[i][1] = fmaf(xv.y, w1a.y, acc[i][1]);
            acc[i][2] = fmaf(xv.y, w1a.z, acc[i][2]);
            acc[i][3] = fmaf(xv.y, w1a.w, acc[i][3]);
            acc[i][4] = fmaf(xv.y, w1b.x, acc[i][4]);
            acc[i][5] = fmaf(xv.y, w1b.y, acc[i][5]);
            acc[i][6] = fmaf(xv.y, w1b.z, acc[i][6]);
            acc[i][7] = fmaf(xv.y, w1b.w, acc[i][7]);
        }
    }

    #pragma unroll
    for (int i = 0; i < 4; ++i) {
        const int row = rb + tr * 4 + i;
        float ps = acc[i][0]*asA.x + acc[i][1]*asA.y + acc[i][2]*asA.z + acc[i][3]*asA.w
                 + acc[i][4]*asB.x + acc[i][5]*asB.y + acc[i][6]*asB.z + acc[i][7]*asB.w;
        float pd = acc[i][0]*adA.x + acc[i][1]*adA.y + acc[i][2]*adA.z + acc[i][3]*adA.w
                 + acc[i][4]*adB.x + acc[i][5]*adB.y + acc[i][6]*adB.z + acc[i][7]*adB.w;
        #pragma unroll
        for (int off = 8; off; off >>= 1) {
            ps += __shfl_down(ps, off, 16);
            pd += __shfl_down(pd, off, 16);
        }
        if (row < nrows) {
            unsigned p0 = (unsigned)f2bf(acc[i][0]) | ((unsigned)f2bf(acc[i][1]) << 16);
            unsigned p1 = (unsigned)f2bf(acc[i][2]) | ((unsigned)f2bf(acc[i][3]) << 16);
            unsigned p2 = (unsigned)f2bf(acc[i][4]) | ((unsigned)f2bf(acc[i][5]) << 16);
            unsigned p3 = (unsigned)f2bf(acc[i][6]) | ((unsigned)f2bf(acc[i][7]) << 16);
            *(uint4*)&H16[(size_t)row * FD + tc * 8] = make_uint4(p0, p1, p2, p3);
            if (tc == 0) { als[row] = ps; ald[row] = pd; }
        }
    }
}

// ---------------------------------------------------------------------------
// CSR build: histogram+rank over dst, exclusive scan, atomic-free scatter.
// ---------------------------------------------------------------------------
__global__ __launch_bounds__(256) void hist_rank_kernel(
    const int* __restrict__ edst, int* __restrict__ deg, int* __restrict__ rank, int E)
{
    int k = blockIdx.x * blockDim.x + threadIdx.x;
    if (k < E) rank[k] = atomicAdd(&deg[edst[k]], 1);
}

__global__ __launch_bounds__(SB) void scan_block_kernel(
    const int* __restrict__ in, int* __restrict__ out, int* __restrict__ bsum, int n)
{
    __shared__ int sh[SB];
    const int tid = threadIdx.x;
    const int i = blockIdx.x * SB + tid;
    int v = (i < n) ? in[i] : 0;
    sh[tid] = v;
    __syncthreads();
    for (int off = 1; off < SB; off <<= 1) {
        int t = (tid >= off) ? sh[tid - off] : 0;
        __syncthreads();
        sh[tid] += t;
        __syncthreads();
    }
    if (i < n) out[i] = sh[tid] - v;
    if (tid == SB - 1) bsum[blockIdx.x] = sh[tid];
}

__global__ __launch_bounds__(SB) void scan_top_kernel(int* __restrict__ bsum, int nb)
{
    __shared__ int sh[SB];
    const int tid = threadIdx.x;
    int v = (tid < nb) ? bsum[tid] : 0;
    sh[tid] = v;
    __syncthreads();
    for (int off = 1; off < SB; off <<= 1) {
        int t = (tid >= off) ? sh[tid - off] : 0;
        __syncthreads();
        sh[tid] += t;
        __syncthreads();
    }
    if (tid < nb) bsum[tid] = sh[tid] - v;
}

__global__ __launch_bounds__(SB) void scan_add_kernel(
    int* __restrict__ rowptr, const int* __restrict__ bsum, int n, int E)
{
    int i = blockIdx.x * SB + threadIdx.x;
    if (i < n) rowptr[i] += bsum[blockIdx.x];
    if (i == 0) rowptr[n] = E;
}

__global__ __launch_bounds__(256) void csr_scatter_kernel(
    const int* __restrict__ esrc, const int* __restrict__ edst,
    const int* __restrict__ rowptr, const int* __restrict__ rank,
    int* __restrict__ esorted, int E)
{
    int k = blockIdx.x * blockDim.x + threadIdx.x;
    if (k >= E) return;
    esorted[rowptr[edst[k]] + rank[k]] = esrc[k];
}

// ---------------------------------------------------------------------------
// Fused GAT aggregation over bf16 features. One node per 32-lane half-wave;
// lane owns 4 cols (uint2 = 4 bf16, 8B/lane). f32 accumulate, f32 softmax.
// ---------------------------------------------------------------------------
__global__ __launch_bounds__(256) void gat_aggregate_kernel(
    const int* __restrict__ rowptr, const int* __restrict__ esorted,
    const float* __restrict__ als, const float* __restrict__ ald,
    const unsigned short* __restrict__ H16, const float* __restrict__ b,
    float* __restrict__ out, int n)
{
    const int d    = (int)((blockIdx.x * 256u + threadIdx.x) >> 5);
    const int lane = threadIdx.x & 31;
    if (d >= n) return;
    const int start = rowptr[d], end = rowptr[d + 1];
    const int deg = end - start;
    const float ald_d = ald[d];
    const int c = lane * 4;

    const uint2 hs = *(const uint2*)&H16[(size_t)d * FD + c];

    float e_self = als[d] + ald_d;
    e_self = fmaxf(e_self, 0.2f * e_self);      // leakyrelu(0.2)

    float e_reg = -INFINITY;
    int src_reg = 0;
    if (lane < deg) {
        src_reg = esorted[start + lane];
        float t = als[src_reg] + ald_d;
        e_reg = fmaxf(t, 0.2f * t);
    }
    float m = e_reg;
    for (int j = start + 32 + lane; j < end; j += 32) {
        float t = als[esorted[j]] + ald_d;
        m = fmaxf(m, fmaxf(t, 0.2f * t));
    }
    #pragma unroll
    for (int off = 16; off; off >>= 1) m = fmaxf(m, __shfl_xor(m, off, 32));
    m = fmaxf(m, e_self);

    const float w_self = __expf(e_self - m);
    const float w_reg  = __expf(e_reg - m);    // 0 for lanes >= deg

    float dsum = w_reg;
    #pragma unroll
    for (int off = 16; off; off >>= 1) dsum += __shfl_xor(dsum, off, 32);
    float denom = dsum + w_self;

    float a0 = w_self * __uint_as_float(hs.x << 16);
    float a1 = w_self * __uint_as_float(hs.x & 0xFFFF0000u);
    float a2 = w_self * __uint_as_float(hs.y << 16);
    float a3 = w_self * __uint_as_float(hs.y & 0xFFFF0000u);

    const int dmin = deg < 32 ? deg : 32;
    int j = 0;
    for (; j + 7 < dmin; j += 8) {
        uint2 hv[8];
        float w[8];
        #pragma unroll
        for (int q = 0; q < 8; ++q) {
            const int s = __shfl(src_reg, j + q, 32);
            w[q] = __shfl(w_reg, j + q, 32);
            hv[q] = *(const uint2*)&H16[(size_t)s * FD + c];
        }
        #pragma unroll
        for (int q = 0; q < 8; ++q) {
            a0 = fmaf(w[q], __uint_as_float(hv[q].x << 16),          a0);
            a1 = fmaf(w[q], __uint_as_float(hv[q].x & 0xFFFF0000u),  a1);
            a2 = fmaf(w[q], __uint_as_float(hv[q].y << 16),          a2);
            a3 = fmaf(w[q], __uint_as_float(hv[q].y & 0xFFFF0000u),  a3);
        }
    }
    for (; j < dmin; ++j) {
        const int   s = __shfl(src_reg, j, 32);
        const float w = __shfl(w_reg, j, 32);
        const uint2 hv = *(const uint2*)&H16[(size_t)s * FD + c];
        a0 = fmaf(w, __uint_as_float(hv.x << 16),         a0);
        a1 = fmaf(w, __uint_as_float(hv.x & 0xFFFF0000u), a1);
        a2 = fmaf(w, __uint_as_float(hv.y << 16),         a2);
        a3 = fmaf(w, __uint_as_float(hv.y & 0xFFFF0000u), a3);
    }
    for (int jj = 32; jj < deg; ++jj) {         // tail (deg > 32)
        const int s = esorted[start + jj];
        float t = als[s] + ald_d;
        t = fmaxf(t, 0.2f * t);
        const float w = __expf(t - m);
        denom += w;
        const uint2 hv = *(const uint2*)&H16[(size_t)s * FD + c];
        a0 = fmaf(w, __uint_as_float(hv.x << 16),         a0);
        a1 = fmaf(w, __uint_as_float(hv.x & 0xFFFF0000u), a1);
        a2 = fmaf(w, __uint_as_float(hv.y << 16),         a2);
        a3 = fmaf(w, __uint_as_float(hv.y & 0xFFFF0000u), a3);
    }
    const float inv = 1.f / denom;
    const float4 bb = *(const float4*)&b[c];
    float4 o;
    o.x = fmaxf(fmaf(a0, inv, bb.x), 0.f);
    o.y = fmaxf(fmaf(a1, inv, bb.y), 0.f);
    o.z = fmaxf(fmaf(a2, inv, bb.z), 0.f);
    o.w = fmaxf(fmaf(a3, inv, bb.w), 0.f);
    *(float4*)&out[(size_t)d * FD + c] = o;
}

// ---------------------------------------------------------------------------
// Mean-pool per graph (batch sorted). One block (512 thr, 4-way rows) per graph.
// ---------------------------------------------------------------------------
__global__ __launch_bounds__(512) void pool_mean_kernel(
    const float* __restrict__ H, const int* __restrict__ batch,
    float* __restrict__ pooled, int n)
{
    __shared__ float sh[3][FD];
    int g = blockIdx.x;
    int lo = 0, hi = n;
    while (lo < hi) { int mid = (lo + hi) >> 1; if (batch[mid] < g) lo = mid + 1; else hi = mid; }
    int start = lo;
    hi = n;
    while (lo < hi) { int mid = (lo + hi) >> 1; if (batch[mid] < g + 1) lo = mid + 1; else hi = mid; }
    int end = lo;
    int col = threadIdx.x & 127;
    int q   = threadIdx.x >> 7;
    float acc = 0.f;
    for (int i = start + q; i < end; i += 4) acc += H[(size_t)i * FD + col];
    if (q) sh[q - 1][col] = acc;
    __syncthreads();
    if (!q) {
        float tot = acc + sh[0][col] + sh[1][col] + sh[2][col];
        float cnt = (float)(end - start);
        pooled[(size_t)g * FD + col] = tot / fmaxf(cnt, 1.f);
    }
}

// logits = [bu | td] @ fc_W + fc_b ; log_softmax. One wave per graph.
__global__ __launch_bounds__(256) void fc_logsoftmax_kernel(
    const float* __restrict__ bu, const float* __restrict__ td,
    const float* __restrict__ Wf, const float* __restrict__ bf,
    float* __restrict__ out, int g)
{
    const int wid  = (int)((blockIdx.x * 256u + threadIdx.x) >> 6);
    const int lane = threadIdx.x & 63;
    if (wid >= g) return;
    const float f0 = bu[(size_t)wid * FD + lane];
    const float f1 = bu[(size_t)wid * FD + 64 + lane];
    const float f2 = td[(size_t)wid * FD + lane];
    const float f3 = td[(size_t)wid * FD + 64 + lane];
    const float4 w0 = *(const float4*)&Wf[lane * 4];
    const float4 w1 = *(const float4*)&Wf[(64 + lane) * 4];
    const float4 w2 = *(const float4*)&Wf[(128 + lane) * 4];
    const float4 w3 = *(const float4*)&Wf[(192 + lane) * 4];
    float l0 = f0 * w0.x + f1 * w1.x + f2 * w2.x + f3 * w3.x;
    float l1 = f0 * w0.y + f1 * w1.y + f2 * w2.y + f3 * w3.y;
    float l2 = f0 * w0.z + f1 * w1.z + f2 * w2.z + f3 * w3.z;
    float l3 = f0 * w0.w + f1 * w1.w + f2 * w2.w + f3 * w3.w;
    #pragma unroll
    for (int off = 32; off; off >>= 1) {
        l0 += __shfl_xor(l0, off, 64);
        l1 += __shfl_xor(l1, off, 64);
        l2 += __shfl_xor(l2, off, 64);
        l3 += __shfl_xor(l3, off, 64);
    }
    if (lane == 0) {
        l0 += bf[0]; l1 += bf[1]; l2 += bf[2]; l3 += bf[3];
        float m = fmaxf(fmaxf(l0, l1), fmaxf(l2, l3));
        float ssum = expf(l0 - m) + expf(l1 - m) + expf(l2 - m) + expf(l3 - m);
        float ls = logf(ssum);
        out[(size_t)wid * 4 + 0] = l0 - m - ls;
        out[(size_t)wid * 4 + 1] = l1 - m - ls;
        out[(size_t)wid * 4 + 2] = l2 - m - ls;
        out[(size_t)wid * 4 + 3] = l3 - m - ls;
    }
}

extern "C" void kernel_launch(void* const* d_in, const int* in_sizes, int n_in,
                              void* d_out, int out_size, void* d_ws, size_t ws_size,
                              hipStream_t stream)
{
    const float* x      = (const float*)d_in[0];
    const int*   td_ei  = (const int*)d_in[1];
    const int*   bu_ei  = (const int*)d_in[2];
    const int*   batch  = (const int*)d_in[3];
    const float* fc_W   = (const float*)d_in[20];
    const float* fc_b   = (const float*)d_in[21];

    const int N = in_sizes[0] / FD;
    const int E = in_sizes[1] / 2;
    const int G = out_size / 4;
    const int nb = (N + SB - 1) / SB;

    char* p = (char*)d_ws;
    unsigned short* h16 = (unsigned short*)p; p += roundup256((size_t)N * FD * 2);
    float* bufB = (float*)p;  p += roundup256((size_t)N * FD * 4);
    float* als  = (float*)p;  p += roundup256((size_t)N * 4);
    float* ald  = (float*)p;  p += roundup256((size_t)N * 4);
    int* rowptr = (int*)p;    p += roundup256((size_t)(N + 1) * 4);
    int* esorted = (int*)p;   p += roundup256((size_t)E * 4);
    int* erank  = (int*)p;    p += roundup256((size_t)E * 4);
    int* deg    = (int*)p;    p += roundup256((size_t)N * 4);
    int* bsum   = (int*)p;    p += roundup256((size_t)SB * 4);
    float* pooled_td = (float*)p; p += roundup256((size_t)G * FD * 4);
    float* pooled_bu = (float*)p; p += roundup256((size_t)G * FD * 4);

    const dim3 blk256(256);
    const dim3 gGemm((N + 63) / 64);
    const dim3 gAgg((N + 7) / 8);       // 8 nodes (half-waves) per 256-thread block
    const dim3 gE((E + 255) / 256);

    auto build_csr = [&](const int* ei) {
        const int* esrc = ei;
        const int* edst = ei + E;
        hipMemsetAsync(deg, 0, (size_t)N * 4, stream);
        hist_rank_kernel<<<gE, blk256, 0, stream>>>(edst, deg, erank, E);
        scan_block_kernel<<<dim3(nb), dim3(SB), 0, stream>>>(deg, rowptr, bsum, N);
        scan_top_kernel<<<dim3(1), dim3(SB), 0, stream>>>(bsum, nb);
        scan_add_kernel<<<dim3(nb), dim3(SB), 0, stream>>>(rowptr, bsum, N, E);
        csr_scatter_kernel<<<gE, blk256, 0, stream>>>(esrc, edst, rowptr, erank, esorted, E);
    };

    auto run_layer = [&](const float* Xin, const float* W, const float* as_,
                         const float* ad_, const float* b_, float* obuf) {
        gemm_al_kernel<<<gGemm, blk256, 0, stream>>>(Xin, W, as_, ad_, h16, als, ald, N);
        gat_aggregate_kernel<<<gAgg, blk256, 0, stream>>>(rowptr, esorted, als, ald, h16, b_, obuf, N);
    };

    auto run_branch = [&](const int* ei, int base, float* pooled) {
        const float* W1  = (const float*)d_in[base + 0];
        const float* as1 = (const float*)d_in[base + 1];
        const float* ad1 = (const float*)d_in[base + 2];
        const float* b1  = (const float*)d_in[base + 3];
        const float* W2  = (const float*)d_in[base + 4];
        const float* as2 = (const float*)d_in[base + 5];
        const float* ad2 = (const float*)d_in[base + 6];
        const float* b2  = (const float*)d_in[base + 7];
        build_csr(ei);
        run_layer(x, W1, as1, ad1, b1, bufB);       // layer 1: x -> h16 -> bufB
        run_layer(bufB, W2, as2, ad2, b2, bufB);    // layer 2: bufB -> h16 -> bufB
        pool_mean_kernel<<<dim3(G), dim3(512), 0, stream>>>(bufB, batch, pooled, N);
    };

    run_branch(td_ei, 4, pooled_td);
    run_branch(bu_ei, 12, pooled_bu);

    fc_logsoftmax_kernel<<<dim3((G + 3) / 4), blk256, 0, stream>>>(
        pooled_bu, pooled_td, fc_W, fc_b, (float*)d_out, G);
}

// Round 7
// 604.804 us; speedup vs baseline: 20.8523x; 1.2943x over previous
//
#include <hip/hip_runtime.h>

#define FD 128
#define SB 512

typedef __attribute__((ext_vector_type(8))) short bf16x8;
typedef __attribute__((ext_vector_type(4))) float f32x4;

static inline size_t roundup256(size_t x) { return (x + 255) & ~(size_t)255; }

// float -> bf16 with round-to-nearest-even
__device__ __forceinline__ unsigned short f2bf(float f) {
    unsigned u = __float_as_uint(f);
    u += 0x7FFFu + ((u >> 16) & 1u);
    return (unsigned short)(u >> 16);
}
__device__ __forceinline__ float bflo(unsigned v) { return __uint_as_float(v << 16); }
__device__ __forceinline__ float bfhi(unsigned v) { return __uint_as_float(v & 0xFFFF0000u); }

// ---------------------------------------------------------------------------
// x (f32) -> bf16, 8 elems/thread
// ---------------------------------------------------------------------------
__global__ __launch_bounds__(256) void f32_to_bf16_kernel(
    const float* __restrict__ in, unsigned short* __restrict__ out, int n8)
{
    int i = blockIdx.x * 256 + threadIdx.x;
    if (i >= n8) return;
    const float4 v0 = ((const float4*)in)[(size_t)i * 2];
    const float4 v1 = ((const float4*)in)[(size_t)i * 2 + 1];
    uint4 o;
    o.x = (unsigned)f2bf(v0.x) | ((unsigned)f2bf(v0.y) << 16);
    o.y = (unsigned)f2bf(v0.z) | ((unsigned)f2bf(v0.w) << 16);
    o.z = (unsigned)f2bf(v1.x) | ((unsigned)f2bf(v1.y) << 16);
    o.w = (unsigned)f2bf(v1.z) | ((unsigned)f2bf(v1.w) << 16);
    ((uint4*)out)[i] = o;
}

// ---------------------------------------------------------------------------
// MFMA GEMM: h = Xb[nrows,128](bf16) @ W[128,128](f32->bf16);
// writes h as bf16 + fused al_s/al_d (f32, from f32 accumulators).
// Block: 256 thr = 4 waves, 64 rows; wave = 16-row strip x 8 col-tiles.
// W staged per block into fragment-ordered bf16 LDS.
// Fragment layouts (mfma_f32_16x16x32_bf16, m89-verified C/D):
//   A: lane l holds A[l&15][8*(l>>4)+j]   B: B[8*(l>>4)+j][l&15]
//   D: row=(l>>4)*4+reg, col=l&15
// ---------------------------------------------------------------------------
__global__ __launch_bounds__(256) void gemm_mfma_kernel(
    const unsigned short* __restrict__ Xb, const float* __restrict__ W,
    const float* __restrict__ a_s, const float* __restrict__ a_d,
    unsigned short* __restrict__ H16, float* __restrict__ als, float* __restrict__ ald,
    int nrows)
{
    __shared__ unsigned short Wb[FD * FD];   // 32 KB, fragment-ordered
    const int tid = threadIdx.x;

    // stage W: coalesced f32 read, scatter bf16 into fragment order
    #pragma unroll 4
    for (int i = 0; i < 64; ++i) {
        const int flat = i * 256 + tid;          // k*128 + n
        const int k = flat >> 7, n = flat & 127;
        const int dest = ((((n >> 4) * 4 + (k >> 5)) * 4 + ((k >> 3) & 3)) * 16 + (n & 15)) * 8 + (k & 7);
        Wb[dest] = f2bf(W[flat]);
    }

    const int w  = tid >> 6;
    const int l  = tid & 63;
    const int lg = l >> 4;
    const int cl = l & 15;
    const int rb = blockIdx.x * 64 + w * 16;

    // A fragments: 4 k-steps, register resident, reused across 8 col-tiles
    bf16x8 a[4];
    {
        const int r = rb + cl;
        if (r < nrows) {
            const unsigned short* xp = Xb + (size_t)r * FD + lg * 8;
            #pragma unroll
            for (int ks = 0; ks < 4; ++ks) a[ks] = *(const bf16x8*)(xp + ks * 32);
        } else {
            #pragma unroll
            for (int ks = 0; ks < 4; ++ks)
                #pragma unroll
                for (int j = 0; j < 8; ++j) a[ks][j] = 0;
        }
    }

    f32x4 acc[8];
    #pragma unroll
    for (int t = 0; t < 8; ++t)
        #pragma unroll
        for (int j = 0; j < 4; ++j) acc[t][j] = 0.f;

    __syncthreads();

    #pragma unroll
    for (int t = 0; t < 8; ++t) {
        #pragma unroll
        for (int ks = 0; ks < 4; ++ks) {
            const bf16x8 b = *(const bf16x8*)&Wb[(((t * 4 + ks) * 4 + lg) * 16 + cl) * 8];
            acc[t] = __builtin_amdgcn_mfma_f32_16x16x32_bf16(a[ks], b, acc[t], 0, 0, 0);
        }
    }

    // epilogue: bf16 store + fused als/ald
    float asv[8], adv[8];
    #pragma unroll
    for (int t = 0; t < 8; ++t) { asv[t] = a_s[t * 16 + cl]; adv[t] = a_d[t * 16 + cl]; }

    #pragma unroll
    for (int jj = 0; jj < 4; ++jj) {
        const int row = rb + 4 * lg + jj;
        float ps = 0.f, pd = 0.f;
        #pragma unroll
        for (int t = 0; t < 8; ++t) {
            ps = fmaf(acc[t][jj], asv[t], ps);
            pd = fmaf(acc[t][jj], adv[t], pd);
        }
        #pragma unroll
        for (int off = 8; off; off >>= 1) {
            ps += __shfl_down(ps, off, 16);
            pd += __shfl_down(pd, off, 16);
        }
        if (row < nrows) {
            #pragma unroll
            for (int t = 0; t < 8; ++t)
                H16[(size_t)row * FD + t * 16 + cl] = f2bf(acc[t][jj]);
            if (cl == 0) { als[row] = ps; ald[row] = pd; }
        }
    }
}

// ---------------------------------------------------------------------------
// CSR build: histogram+rank over dst, exclusive scan, atomic-free scatter.
// ---------------------------------------------------------------------------
__global__ __launch_bounds__(256) void hist_rank_kernel(
    const int* __restrict__ edst, int* __restrict__ deg, int* __restrict__ rank, int E)
{
    int k = blockIdx.x * blockDim.x + threadIdx.x;
    if (k < E) rank[k] = atomicAdd(&deg[edst[k]], 1);
}

__global__ __launch_bounds__(SB) void scan_block_kernel(
    const int* __restrict__ in, int* __restrict__ out, int* __restrict__ bsum, int n)
{
    __shared__ int sh[SB];
    const int tid = threadIdx.x;
    const int i = blockIdx.x * SB + tid;
    int v = (i < n) ? in[i] : 0;
    sh[tid] = v;
    __syncthreads();
    for (int off = 1; off < SB; off <<= 1) {
        int t = (tid >= off) ? sh[tid - off] : 0;
        __syncthreads();
        sh[tid] += t;
        __syncthreads();
    }
    if (i < n) out[i] = sh[tid] - v;
    if (tid == SB - 1) bsum[blockIdx.x] = sh[tid];
}

__global__ __launch_bounds__(SB) void scan_top_kernel(int* __restrict__ bsum, int nb)
{
    __shared__ int sh[SB];
    const int tid = threadIdx.x;
    int v = (tid < nb) ? bsum[tid] : 0;
    sh[tid] = v;
    __syncthreads();
    for (int off = 1; off < SB; off <<= 1) {
        int t = (tid >= off) ? sh[tid - off] : 0;
        __syncthreads();
        sh[tid] += t;
        __syncthreads();
    }
    if (tid < nb) bsum[tid] = sh[tid] - v;
}

__global__ __launch_bounds__(SB) void scan_add_kernel(
    int* __restrict__ rowptr, const int* __restrict__ bsum, int n, int E)
{
    int i = blockIdx.x * SB + threadIdx.x;
    if (i < n) rowptr[i] += bsum[blockIdx.x];
    if (i == 0) rowptr[n] = E;
}

__global__ __launch_bounds__(256) void csr_scatter_kernel(
    const int* __restrict__ esrc, const int* __restrict__ edst,
    const int* __restrict__ rowptr, const int* __restrict__ rank,
    int* __restrict__ esorted, int E)
{
    int k = blockIdx.x * blockDim.x + threadIdx.x;
    if (k >= E) return;
    esorted[rowptr[edst[k]] + rank[k]] = esrc[k];
}

// ---------------------------------------------------------------------------
// Fused GAT aggregation over bf16 features; bf16 output (bias+ReLU applied).
// One node per 32-lane half-wave; lane owns 4 cols (uint2 = 4 bf16).
// ---------------------------------------------------------------------------
__global__ __launch_bounds__(256) void gat_aggregate_kernel(
    const int* __restrict__ rowptr, const int* __restrict__ esorted,
    const float* __restrict__ als, const float* __restrict__ ald,
    const unsigned short* __restrict__ H16, const float* __restrict__ b,
    unsigned short* __restrict__ out16, int n)
{
    const int d    = (int)((blockIdx.x * 256u + threadIdx.x) >> 5);
    const int lane = threadIdx.x & 31;
    if (d >= n) return;
    const int start = rowptr[d], end = rowptr[d + 1];
    const int deg = end - start;
    const float ald_d = ald[d];
    const int c = lane * 4;

    const uint2 hs = *(const uint2*)&H16[(size_t)d * FD + c];

    float e_self = als[d] + ald_d;
    e_self = fmaxf(e_self, 0.2f * e_self);

    float e_reg = -INFINITY;
    int src_reg = 0;
    if (lane < deg) {
        src_reg = esorted[start + lane];
        float t = als[src_reg] + ald_d;
        e_reg = fmaxf(t, 0.2f * t);
    }
    float m = e_reg;
    for (int j = start + 32 + lane; j < end; j += 32) {
        float t = als[esorted[j]] + ald_d;
        m = fmaxf(m, fmaxf(t, 0.2f * t));
    }
    #pragma unroll
    for (int off = 16; off; off >>= 1) m = fmaxf(m, __shfl_xor(m, off, 32));
    m = fmaxf(m, e_self);

    const float w_self = __expf(e_self - m);
    const float w_reg  = __expf(e_reg - m);

    float dsum = w_reg;
    #pragma unroll
    for (int off = 16; off; off >>= 1) dsum += __shfl_xor(dsum, off, 32);
    float denom = dsum + w_self;

    float a0 = w_self * bflo(hs.x);
    float a1 = w_self * bfhi(hs.x);
    float a2 = w_self * bflo(hs.y);
    float a3 = w_self * bfhi(hs.y);

    const int dmin = deg < 32 ? deg : 32;
    int j = 0;
    for (; j + 7 < dmin; j += 8) {
        uint2 hv[8];
        float w[8];
        #pragma unroll
        for (int q = 0; q < 8; ++q) {
            const int s = __shfl(src_reg, j + q, 32);
            w[q] = __shfl(w_reg, j + q, 32);
            hv[q] = *(const uint2*)&H16[(size_t)s * FD + c];
        }
        #pragma unroll
        for (int q = 0; q < 8; ++q) {
            a0 = fmaf(w[q], bflo(hv[q].x), a0);
            a1 = fmaf(w[q], bfhi(hv[q].x), a1);
            a2 = fmaf(w[q], bflo(hv[q].y), a2);
            a3 = fmaf(w[q], bfhi(hv[q].y), a3);
        }
    }
    for (; j < dmin; ++j) {
        const int   s = __shfl(src_reg, j, 32);
        const float w = __shfl(w_reg, j, 32);
        const uint2 hv = *(const uint2*)&H16[(size_t)s * FD + c];
        a0 = fmaf(w, bflo(hv.x), a0);
        a1 = fmaf(w, bfhi(hv.x), a1);
        a2 = fmaf(w, bflo(hv.y), a2);
        a3 = fmaf(w, bfhi(hv.y), a3);
    }
    for (int jj = 32; jj < deg; ++jj) {
        const int s = esorted[start + jj];
        float t = als[s] + ald_d;
        t = fmaxf(t, 0.2f * t);
        const float w = __expf(t - m);
        denom += w;
        const uint2 hv = *(const uint2*)&H16[(size_t)s * FD + c];
        a0 = fmaf(w, bflo(hv.x), a0);
        a1 = fmaf(w, bfhi(hv.x), a1);
        a2 = fmaf(w, bflo(hv.y), a2);
        a3 = fmaf(w, bfhi(hv.y), a3);
    }
    const float inv = 1.f / denom;
    const float4 bb = *(const float4*)&b[c];
    const float o0 = fmaxf(fmaf(a0, inv, bb.x), 0.f);
    const float o1 = fmaxf(fmaf(a1, inv, bb.y), 0.f);
    const float o2 = fmaxf(fmaf(a2, inv, bb.z), 0.f);
    const float o3 = fmaxf(fmaf(a3, inv, bb.w), 0.f);
    uint2 ov;
    ov.x = (unsigned)f2bf(o0) | ((unsigned)f2bf(o1) << 16);
    ov.y = (unsigned)f2bf(o2) | ((unsigned)f2bf(o3) << 16);
    *(uint2*)&out16[(size_t)d * FD + c] = ov;
}

// ---------------------------------------------------------------------------
// Mean-pool per graph over bf16 features (batch sorted). 256 thr, 4-way rows.
// ---------------------------------------------------------------------------
__global__ __launch_bounds__(256) void pool_mean_kernel(
    const unsigned short* __restrict__ Hb, const int* __restrict__ batch,
    float* __restrict__ pooled, int n)
{
    __shared__ float sh[3][FD];
    int g = blockIdx.x;
    int lo = 0, hi = n;
    while (lo < hi) { int mid = (lo + hi) >> 1; if (batch[mid] < g) lo = mid + 1; else hi = mid; }
    int start = lo;
    hi = n;
    while (lo < hi) { int mid = (lo + hi) >> 1; if (batch[mid] < g + 1) lo = mid + 1; else hi = mid; }
    int end = lo;
    const int cp = threadIdx.x & 63;    // column pair
    const int q  = threadIdx.x >> 6;    // 0..3
    float ax = 0.f, ay = 0.f;
    for (int i = start + q; i < end; i += 4) {
        unsigned v = ((const unsigned*)Hb)[(size_t)i * 64 + cp];
        ax += bflo(v);
        ay += bfhi(v);
    }
    if (q) { sh[q - 1][cp * 2] = ax; sh[q - 1][cp * 2 + 1] = ay; }
    __syncthreads();
    if (!q) {
        float tx = ax + sh[0][cp * 2] + sh[1][cp * 2] + sh[2][cp * 2];
        float ty = ay + sh[0][cp * 2 + 1] + sh[1][cp * 2 + 1] + sh[2][cp * 2 + 1];
        float inv = 1.f / fmaxf((float)(end - start), 1.f);
        pooled[(size_t)g * FD + cp * 2]     = tx * inv;
        pooled[(size_t)g * FD + cp * 2 + 1] = ty * inv;
    }
}

// logits = [bu | td] @ fc_W + fc_b ; log_softmax. One wave per graph.
__global__ __launch_bounds__(256) void fc_logsoftmax_kernel(
    const float* __restrict__ bu, const float* __restrict__ td,
    const float* __restrict__ Wf, const float* __restrict__ bf,
    float* __restrict__ out, int g)
{
    const int wid  = (int)((blockIdx.x * 256u + threadIdx.x) >> 6);
    const int lane = threadIdx.x & 63;
    if (wid >= g) return;
    const float f0 = bu[(size_t)wid * FD + lane];
    const float f1 = bu[(size_t)wid * FD + 64 + lane];
    const float f2 = td[(size_t)wid * FD + lane];
    const float f3 = td[(size_t)wid * FD + 64 + lane];
    const float4 w0 = *(const float4*)&Wf[lane * 4];
    const float4 w1 = *(const float4*)&Wf[(64 + lane) * 4];
    const float4 w2 = *(const float4*)&Wf[(128 + lane) * 4];
    const float4 w3 = *(const float4*)&Wf[(192 + lane) * 4];
    float l0 = f0 * w0.x + f1 * w1.x + f2 * w2.x + f3 * w3.x;
    float l1 = f0 * w0.y + f1 * w1.y + f2 * w2.y + f3 * w3.y;
    float l2 = f0 * w0.z + f1 * w1.z + f2 * w2.z + f3 * w3.z;
    float l3 = f0 * w0.w + f1 * w1.w + f2 * w2.w + f3 * w3.w;
    #pragma unroll
    for (int off = 32; off; off >>= 1) {
        l0 += __shfl_xor(l0, off, 64);
        l1 += __shfl_xor(l1, off, 64);
        l2 += __shfl_xor(l2, off, 64);
        l3 += __shfl_xor(l3, off, 64);
    }
    if (lane == 0) {
        l0 += bf[0]; l1 += bf[1]; l2 += bf[2]; l3 += bf[3];
        float m = fmaxf(fmaxf(l0, l1), fmaxf(l2, l3));
        float ssum = expf(l0 - m) + expf(l1 - m) + expf(l2 - m) + expf(l3 - m);
        float ls = logf(ssum);
        out[(size_t)wid * 4 + 0] = l0 - m - ls;
        out[(size_t)wid * 4 + 1] = l1 - m - ls;
        out[(size_t)wid * 4 + 2] = l2 - m - ls;
        out[(size_t)wid * 4 + 3] = l3 - m - ls;
    }
}

extern "C" void kernel_launch(void* const* d_in, const int* in_sizes, int n_in,
                              void* d_out, int out_size, void* d_ws, size_t ws_size,
                              hipStream_t stream)
{
    const float* x      = (const float*)d_in[0];
    const int*   td_ei  = (const int*)d_in[1];
    const int*   bu_ei  = (const int*)d_in[2];
    const int*   batch  = (const int*)d_in[3];
    const float* fc_W   = (const float*)d_in[20];
    const float* fc_b   = (const float*)d_in[21];

    const int N = in_sizes[0] / FD;
    const int E = in_sizes[1] / 2;
    const int G = out_size / 4;
    const int nb = (N + SB - 1) / SB;

    char* p = (char*)d_ws;
    unsigned short* xb16 = (unsigned short*)p; p += roundup256((size_t)N * FD * 2);
    unsigned short* h16  = (unsigned short*)p; p += roundup256((size_t)N * FD * 2);
    unsigned short* o16  = (unsigned short*)p; p += roundup256((size_t)N * FD * 2);
    float* als  = (float*)p;  p += roundup256((size_t)N * 4);
    float* ald  = (float*)p;  p += roundup256((size_t)N * 4);
    int* rowptr = (int*)p;    p += roundup256((size_t)(N + 1) * 4);
    int* esorted = (int*)p;   p += roundup256((size_t)E * 4);
    int* erank  = (int*)p;    p += roundup256((size_t)E * 4);
    int* deg    = (int*)p;    p += roundup256((size_t)N * 4);
    int* bsum   = (int*)p;    p += roundup256((size_t)SB * 4);
    float* pooled_td = (float*)p; p += roundup256((size_t)G * FD * 4);
    float* pooled_bu = (float*)p; p += roundup256((size_t)G * FD * 4);

    const dim3 blk256(256);
    const dim3 gGemm((N + 63) / 64);
    const dim3 gAgg((N + 7) / 8);
    const dim3 gE((E + 255) / 256);
    const int n8 = N * FD / 8;

    // x -> bf16 once (shared by both branches)
    f32_to_bf16_kernel<<<dim3((n8 + 255) / 256), blk256, 0, stream>>>(x, xb16, n8);

    auto build_csr = [&](const int* ei) {
        const int* esrc = ei;
        const int* edst = ei + E;
        hipMemsetAsync(deg, 0, (size_t)N * 4, stream);
        hist_rank_kernel<<<gE, blk256, 0, stream>>>(edst, deg, erank, E);
        scan_block_kernel<<<dim3(nb), dim3(SB), 0, stream>>>(deg, rowptr, bsum, N);
        scan_top_kernel<<<dim3(1), dim3(SB), 0, stream>>>(bsum, nb);
        scan_add_kernel<<<dim3(nb), dim3(SB), 0, stream>>>(rowptr, bsum, N, E);
        csr_scatter_kernel<<<gE, blk256, 0, stream>>>(esrc, edst, rowptr, erank, esorted, E);
    };

    auto run_layer = [&](const unsigned short* Xin, const float* W, const float* as_,
                         const float* ad_, const float* b_, unsigned short* obuf) {
        gemm_mfma_kernel<<<gGemm, blk256, 0, stream>>>(Xin, W, as_, ad_, h16, als, ald, N);
        gat_aggregate_kernel<<<gAgg, blk256, 0, stream>>>(rowptr, esorted, als, ald, h16, b_, obuf, N);
    };

    auto run_branch = [&](const int* ei, int base, float* pooled) {
        const float* W1  = (const float*)d_in[base + 0];
        const float* as1 = (const float*)d_in[base + 1];
        const float* ad1 = (const float*)d_in[base + 2];
        const float* b1  = (const float*)d_in[base + 3];
        const float* W2  = (const float*)d_in[base + 4];
        const float* as2 = (const float*)d_in[base + 5];
        const float* ad2 = (const float*)d_in[base + 6];
        const float* b2  = (const float*)d_in[base + 7];
        build_csr(ei);
        run_layer(xb16, W1, as1, ad1, b1, o16);   // layer 1: xb16 -> h16 -> o16
        run_layer(o16,  W2, as2, ad2, b2, o16);   // layer 2: o16 -> h16 -> o16
        pool_mean_kernel<<<dim3(G), blk256, 0, stream>>>(o16, batch, pooled, N);
    };

    run_branch(td_ei, 4, pooled_td);
    run_branch(bu_ei, 12, pooled_bu);

    fc_logsoftmax_kernel<<<dim3((G + 3) / 4), blk256, 0, stream>>>(
        pooled_bu, pooled_td, fc_W, fc_b, (float*)d_out, G);
}

// Round 8
// 531.998 us; speedup vs baseline: 23.7061x; 1.1369x over previous
//
#include <hip/hip_runtime.h>

#define FD 128
#define SB 512

typedef __attribute__((ext_vector_type(8))) short bf16x8;
typedef __attribute__((ext_vector_type(4))) float f32x4;

static inline size_t roundup256(size_t x) { return (x + 255) & ~(size_t)255; }

// float -> bf16 round-to-nearest-even
__device__ __forceinline__ unsigned short f2bf(float f) {
    unsigned u = __float_as_uint(f);
    u += 0x7FFFu + ((u >> 16) & 1u);
    return (unsigned short)(u >> 16);
}
__device__ __forceinline__ float bflo(unsigned v) { return __uint_as_float(v << 16); }
__device__ __forceinline__ float bfhi(unsigned v) { return __uint_as_float(v & 0xFFFF0000u); }

// ---------------------------------------------------------------------------
// W (f32 [128][128]) -> bf16 MFMA-fragment order. 4 matrices in one launch.
// Fragment order (verified R7): frag(t,ks,lg,cl)[j] = W[k][n],
//   t=n>>4, ks=k>>5, lg=(k>>3)&3, cl=n&15, j=k&7.
// ---------------------------------------------------------------------------
__global__ __launch_bounds__(256) void wprep_kernel(
    const float* __restrict__ w0, const float* __restrict__ w1,
    const float* __restrict__ w2, const float* __restrict__ w3,
    unsigned short* __restrict__ out)   // [4][16384]
{
    const int widx = blockIdx.y;
    const float* src = (widx == 0) ? w0 : (widx == 1) ? w1 : (widx == 2) ? w2 : w3;
    const int flat = blockIdx.x * 256 + threadIdx.x;   // k*128 + n
    const int k = flat >> 7, n = flat & 127;
    const int dest = ((((n >> 4) * 4 + (k >> 5)) * 4 + ((k >> 3) & 3)) * 16 + (n & 15)) * 8 + (k & 7);
    out[widx * 16384 + dest] = f2bf(src[flat]);
}

// ---------------------------------------------------------------------------
// MFMA GEMM, both branches (blockIdx.y). h = A[lr,:] @ W_br; bf16 out + als/ald.
// A from f32 (layer1, shared x: xbstride=0) or bf16 (layer2, xbstride=N).
// No LDS: B-frags read from pre-formatted global Wfrag (L2-resident).
// ---------------------------------------------------------------------------
template<bool A_F32>
__global__ __launch_bounds__(256) void gemm_mfma_kernel(
    const float* __restrict__ Xf, const unsigned short* __restrict__ Xb,
    const unsigned short* __restrict__ Wfrag,   // [2][16384] for this layer
    const float* __restrict__ as0, const float* __restrict__ ad0,
    const float* __restrict__ as1, const float* __restrict__ ad1,
    unsigned short* __restrict__ H16, float* __restrict__ als, float* __restrict__ ald,
    int nrows, int xbstride)
{
    const int tid = threadIdx.x;
    const int br  = blockIdx.y;
    const int w = tid >> 6, l = tid & 63, lg = l >> 4, cl = l & 15;
    const int lr0 = blockIdx.x * 64 + w * 16;      // local (per-branch) strip base
    const int lr  = lr0 + cl;                      // local row for A-frags
    const unsigned short* Wb = Wfrag + br * 16384;
    const float* a_s = br ? as1 : as0;
    const float* a_d = br ? ad1 : ad0;

    bf16x8 a[4];
    if (lr < nrows) {
        if (A_F32) {
            const float* xp = Xf + (size_t)(br * xbstride + lr) * FD + lg * 8;
            #pragma unroll
            for (int ks = 0; ks < 4; ++ks) {
                const float4 v0 = *(const float4*)(xp + ks * 32);
                const float4 v1 = *(const float4*)(xp + ks * 32 + 4);
                bf16x8 t;
                t[0] = (short)f2bf(v0.x); t[1] = (short)f2bf(v0.y);
                t[2] = (short)f2bf(v0.z); t[3] = (short)f2bf(v0.w);
                t[4] = (short)f2bf(v1.x); t[5] = (short)f2bf(v1.y);
                t[6] = (short)f2bf(v1.z); t[7] = (short)f2bf(v1.w);
                a[ks] = t;
            }
        } else {
            const unsigned short* xp = Xb + (size_t)(br * xbstride + lr) * FD + lg * 8;
            #pragma unroll
            for (int ks = 0; ks < 4; ++ks) a[ks] = *(const bf16x8*)(xp + ks * 32);
        }
    } else {
        #pragma unroll
        for (int ks = 0; ks < 4; ++ks)
            #pragma unroll
            for (int j = 0; j < 8; ++j) a[ks][j] = 0;
    }

    f32x4 acc[8];
    #pragma unroll
    for (int t = 0; t < 8; ++t)
        #pragma unroll
        for (int j = 0; j < 4; ++j) acc[t][j] = 0.f;

    #pragma unroll
    for (int t = 0; t < 8; ++t) {
        #pragma unroll
        for (int ks = 0; ks < 4; ++ks) {
            const bf16x8 b = *(const bf16x8*)&Wb[(((t * 4 + ks) * 4 + lg) * 16 + cl) * 8];
            acc[t] = __builtin_amdgcn_mfma_f32_16x16x32_bf16(a[ks], b, acc[t], 0, 0, 0);
        }
    }

    float asv[8], adv[8];
    #pragma unroll
    for (int t = 0; t < 8; ++t) { asv[t] = a_s[t * 16 + cl]; adv[t] = a_d[t * 16 + cl]; }

    #pragma unroll
    for (int jj = 0; jj < 4; ++jj) {
        const int lrow = lr0 + 4 * lg + jj;        // local row of this D element
        float ps = 0.f, pd = 0.f;
        #pragma unroll
        for (int t = 0; t < 8; ++t) {
            ps = fmaf(acc[t][jj], asv[t], ps);
            pd = fmaf(acc[t][jj], adv[t], pd);
        }
        #pragma unroll
        for (int off = 8; off; off >>= 1) {
            ps += __shfl_down(ps, off, 16);
            pd += __shfl_down(pd, off, 16);
        }
        if (lrow < nrows) {
            const size_t grow = (size_t)br * nrows + lrow;   // global row
            #pragma unroll
            for (int t = 0; t < 8; ++t)
                H16[grow * FD + t * 16 + cl] = f2bf(acc[t][jj]);
            if (cl == 0) { als[grow] = ps; ald[grow] = pd; }
        }
    }
}

// ---------------------------------------------------------------------------
// Fused CSR for BOTH branches: bins/rows indexed branch*N + node.
// ---------------------------------------------------------------------------
__global__ __launch_bounds__(256) void hist_rank_kernel(
    const int* __restrict__ td_ei, const int* __restrict__ bu_ei,
    int* __restrict__ deg, int* __restrict__ rank, int E, int N)
{
    int k = blockIdx.x * blockDim.x + threadIdx.x;
    if (k >= 2 * E) return;
    int d = (k < E) ? td_ei[E + k] : (N + bu_ei[E + (k - E)]);
    rank[k] = atomicAdd(&deg[d], 1);
}

__global__ __launch_bounds__(SB) void scan_block_kernel(
    const int* __restrict__ in, int* __restrict__ out, int* __restrict__ bsum, int n)
{
    __shared__ int sh[SB];
    const int tid = threadIdx.x;
    const int i = blockIdx.x * SB + tid;
    int v = (i < n) ? in[i] : 0;
    sh[tid] = v;
    __syncthreads();
    for (int off = 1; off < SB; off <<= 1) {
        int t = (tid >= off) ? sh[tid - off] : 0;
        __syncthreads();
        sh[tid] += t;
        __syncthreads();
    }
    if (i < n) out[i] = sh[tid] - v;
    if (tid == SB - 1) bsum[blockIdx.x] = sh[tid];
}

__global__ __launch_bounds__(SB) void scan_top_kernel(int* __restrict__ bsum, int nb)
{
    __shared__ int sh[SB];
    const int tid = threadIdx.x;
    int v = (tid < nb) ? bsum[tid] : 0;
    sh[tid] = v;
    __syncthreads();
    for (int off = 1; off < SB; off <<= 1) {
        int t = (tid >= off) ? sh[tid - off] : 0;
        __syncthreads();
        sh[tid] += t;
        __syncthreads();
    }
    if (tid < nb) bsum[tid] = sh[tid] - v;
}

__global__ __launch_bounds__(SB) void scan_add_kernel(
    int* __restrict__ rowptr, const int* __restrict__ bsum, int n, int total)
{
    int i = blockIdx.x * SB + threadIdx.x;
    if (i < n) rowptr[i] += bsum[blockIdx.x];
    if (i == 0) rowptr[n] = total;
}

__global__ __launch_bounds__(256) void csr_scatter_kernel(
    const int* __restrict__ td_ei, const int* __restrict__ bu_ei,
    const int* __restrict__ rowptr, const int* __restrict__ rank,
    int* __restrict__ esorted, int E, int N)
{
    int k = blockIdx.x * blockDim.x + threadIdx.x;
    if (k >= 2 * E) return;
    int s, d;
    if (k < E) { s = td_ei[k];           d = td_ei[E + k]; }
    else       { s = N + bu_ei[k - E];   d = N + bu_ei[E + (k - E)]; }
    esorted[rowptr[d] + rank[k]] = s;    // global row id
}

// ---------------------------------------------------------------------------
// Fused GAT aggregation over bf16 features, both branches (2N nodes).
// One node per 32-lane half-wave; lane owns 4 cols (uint2 = 4 bf16).
// ---------------------------------------------------------------------------
__global__ __launch_bounds__(256) void gat_aggregate_kernel(
    const int* __restrict__ rowptr, const int* __restrict__ esorted,
    const float* __restrict__ als, const float* __restrict__ ald,
    const unsigned short* __restrict__ H16,
    const float* __restrict__ b0, const float* __restrict__ b1,
    unsigned short* __restrict__ out16, int n2, int N)
{
    const int d    = (int)((blockIdx.x * 256u + threadIdx.x) >> 5);
    const int lane = threadIdx.x & 31;
    if (d >= n2) return;
    const int start = rowptr[d], end = rowptr[d + 1];
    const int deg = end - start;
    const float ald_d = ald[d];
    const int c = lane * 4;
    const float* bias = (d < N) ? b0 : b1;

    const uint2 hs = *(const uint2*)&H16[(size_t)d * FD + c];

    float e_self = als[d] + ald_d;
    e_self = fmaxf(e_self, 0.2f * e_self);

    float e_reg = -INFINITY;
    int src_reg = 0;
    if (lane < deg) {
        src_reg = esorted[start + lane];
        float t = als[src_reg] + ald_d;
        e_reg = fmaxf(t, 0.2f * t);
    }
    float m = e_reg;
    for (int j = start + 32 + lane; j < end; j += 32) {
        float t = als[esorted[j]] + ald_d;
        m = fmaxf(m, fmaxf(t, 0.2f * t));
    }
    #pragma unroll
    for (int off = 16; off; off >>= 1) m = fmaxf(m, __shfl_xor(m, off, 32));
    m = fmaxf(m, e_self);

    const float w_self = __expf(e_self - m);
    const float w_reg  = __expf(e_reg - m);

    float dsum = w_reg;
    #pragma unroll
    for (int off = 16; off; off >>= 1) dsum += __shfl_xor(dsum, off, 32);
    float denom = dsum + w_self;

    float a0 = w_self * bflo(hs.x);
    float a1 = w_self * bfhi(hs.x);
    float a2 = w_self * bflo(hs.y);
    float a3 = w_self * bfhi(hs.y);

    const int dmin = deg < 32 ? deg : 32;
    int j = 0;
    for (; j + 7 < dmin; j += 8) {
        uint2 hv[8];
        float w[8];
        #pragma unroll
        for (int q = 0; q < 8; ++q) {
            const int s = __shfl(src_reg, j + q, 32);
            w[q] = __shfl(w_reg, j + q, 32);
            hv[q] = *(const uint2*)&H16[(size_t)s * FD + c];
        }
        #pragma unroll
        for (int q = 0; q < 8; ++q) {
            a0 = fmaf(w[q], bflo(hv[q].x), a0);
            a1 = fmaf(w[q], bfhi(hv[q].x), a1);
            a2 = fmaf(w[q], bflo(hv[q].y), a2);
            a3 = fmaf(w[q], bfhi(hv[q].y), a3);
        }
    }
    for (; j < dmin; ++j) {
        const int   s = __shfl(src_reg, j, 32);
        const float w = __shfl(w_reg, j, 32);
        const uint2 hv = *(const uint2*)&H16[(size_t)s * FD + c];
        a0 = fmaf(w, bflo(hv.x), a0);
        a1 = fmaf(w, bfhi(hv.x), a1);
        a2 = fmaf(w, bflo(hv.y), a2);
        a3 = fmaf(w, bfhi(hv.y), a3);
    }
    for (int jj = 32; jj < deg; ++jj) {
        const int s = esorted[start + jj];
        float t = als[s] + ald_d;
        t = fmaxf(t, 0.2f * t);
        const float w = __expf(t - m);
        denom += w;
        const uint2 hv = *(const uint2*)&H16[(size_t)s * FD + c];
        a0 = fmaf(w, bflo(hv.x), a0);
        a1 = fmaf(w, bfhi(hv.x), a1);
        a2 = fmaf(w, bflo(hv.y), a2);
        a3 = fmaf(w, bfhi(hv.y), a3);
    }
    const float inv = 1.f / denom;
    const float4 bb = *(const float4*)&bias[c];
    const float o0 = fmaxf(fmaf(a0, inv, bb.x), 0.f);
    const float o1 = fmaxf(fmaf(a1, inv, bb.y), 0.f);
    const float o2 = fmaxf(fmaf(a2, inv, bb.z), 0.f);
    const float o3 = fmaxf(fmaf(a3, inv, bb.w), 0.f);
    uint2 ov;
    ov.x = (unsigned)f2bf(o0) | ((unsigned)f2bf(o1) << 16);
    ov.y = (unsigned)f2bf(o2) | ((unsigned)f2bf(o3) << 16);
    *(uint2*)&out16[(size_t)d * FD + c] = ov;
}

// ---------------------------------------------------------------------------
// Mean-pool per graph, both branches (blockIdx.y). batch sorted, len N.
// ---------------------------------------------------------------------------
__global__ __launch_bounds__(256) void pool_mean_kernel(
    const unsigned short* __restrict__ Hb, const int* __restrict__ batch,
    float* __restrict__ pooled_td, float* __restrict__ pooled_bu, int n)
{
    __shared__ float sh[3][FD];
    const int g = blockIdx.x;
    const int br = blockIdx.y;
    int lo = 0, hi = n;
    while (lo < hi) { int mid = (lo + hi) >> 1; if (batch[mid] < g) lo = mid + 1; else hi = mid; }
    int start = lo;
    hi = n;
    while (lo < hi) { int mid = (lo + hi) >> 1; if (batch[mid] < g + 1) lo = mid + 1; else hi = mid; }
    int end = lo;
    const int cp = threadIdx.x & 63;
    const int q  = threadIdx.x >> 6;
    const size_t rbase = (size_t)br * n;
    float ax = 0.f, ay = 0.f;
    for (int i = start + q; i < end; i += 4) {
        unsigned v = ((const unsigned*)Hb)[(rbase + i) * 64 + cp];
        ax += bflo(v);
        ay += bfhi(v);
    }
    if (q) { sh[q - 1][cp * 2] = ax; sh[q - 1][cp * 2 + 1] = ay; }
    __syncthreads();
    if (!q) {
        float tx = ax + sh[0][cp * 2] + sh[1][cp * 2] + sh[2][cp * 2];
        float ty = ay + sh[0][cp * 2 + 1] + sh[1][cp * 2 + 1] + sh[2][cp * 2 + 1];
        float inv = 1.f / fmaxf((float)(end - start), 1.f);
        float* out = br ? pooled_bu : pooled_td;
        out[(size_t)g * FD + cp * 2]     = tx * inv;
        out[(size_t)g * FD + cp * 2 + 1] = ty * inv;
    }
}

// logits = [bu | td] @ fc_W + fc_b ; log_softmax. One wave per graph.
__global__ __launch_bounds__(256) void fc_logsoftmax_kernel(
    const float* __restrict__ bu, const float* __restrict__ td,
    const float* __restrict__ Wf, const float* __restrict__ bf,
    float* __restrict__ out, int g)
{
    const int wid  = (int)((blockIdx.x * 256u + threadIdx.x) >> 6);
    const int lane = threadIdx.x & 63;
    if (wid >= g) return;
    const float f0 = bu[(size_t)wid * FD + lane];
    const float f1 = bu[(size_t)wid * FD + 64 + lane];
    const float f2 = td[(size_t)wid * FD + lane];
    const float f3 = td[(size_t)wid * FD + 64 + lane];
    const float4 w0 = *(const float4*)&Wf[lane * 4];
    const float4 w1 = *(const float4*)&Wf[(64 + lane) * 4];
    const float4 w2 = *(const float4*)&Wf[(128 + lane) * 4];
    const float4 w3 = *(const float4*)&Wf[(192 + lane) * 4];
    float l0 = f0 * w0.x + f1 * w1.x + f2 * w2.x + f3 * w3.x;
    float l1 = f0 * w0.y + f1 * w1.y + f2 * w2.y + f3 * w3.y;
    float l2 = f0 * w0.z + f1 * w1.z + f2 * w2.z + f3 * w3.z;
    float l3 = f0 * w0.w + f1 * w1.w + f2 * w2.w + f3 * w3.w;
    #pragma unroll
    for (int off = 32; off; off >>= 1) {
        l0 += __shfl_xor(l0, off, 64);
        l1 += __shfl_xor(l1, off, 64);
        l2 += __shfl_xor(l2, off, 64);
        l3 += __shfl_xor(l3, off, 64);
    }
    if (lane == 0) {
        l0 += bf[0]; l1 += bf[1]; l2 += bf[2]; l3 += bf[3];
        float m = fmaxf(fmaxf(l0, l1), fmaxf(l2, l3));
        float ssum = expf(l0 - m) + expf(l1 - m) + expf(l2 - m) + expf(l3 - m);
        float ls = logf(ssum);
        out[(size_t)wid * 4 + 0] = l0 - m - ls;
        out[(size_t)wid * 4 + 1] = l1 - m - ls;
        out[(size_t)wid * 4 + 2] = l2 - m - ls;
        out[(size_t)wid * 4 + 3] = l3 - m - ls;
    }
}

extern "C" void kernel_launch(void* const* d_in, const int* in_sizes, int n_in,
                              void* d_out, int out_size, void* d_ws, size_t ws_size,
                              hipStream_t stream)
{
    const float* x      = (const float*)d_in[0];
    const int*   td_ei  = (const int*)d_in[1];
    const int*   bu_ei  = (const int*)d_in[2];
    const int*   batch  = (const int*)d_in[3];
    const float* td_W1  = (const float*)d_in[4];
    const float* td_as1 = (const float*)d_in[5];
    const float* td_ad1 = (const float*)d_in[6];
    const float* td_b1  = (const float*)d_in[7];
    const float* td_W2  = (const float*)d_in[8];
    const float* td_as2 = (const float*)d_in[9];
    const float* td_ad2 = (const float*)d_in[10];
    const float* td_b2  = (const float*)d_in[11];
    const float* bu_W1  = (const float*)d_in[12];
    const float* bu_as1 = (const float*)d_in[13];
    const float* bu_ad1 = (const float*)d_in[14];
    const float* bu_b1  = (const float*)d_in[15];
    const float* bu_W2  = (const float*)d_in[16];
    const float* bu_as2 = (const float*)d_in[17];
    const float* bu_ad2 = (const float*)d_in[18];
    const float* bu_b2  = (const float*)d_in[19];
    const float* fc_W   = (const float*)d_in[20];
    const float* fc_b   = (const float*)d_in[21];

    const int N = in_sizes[0] / FD;
    const int E = in_sizes[1] / 2;
    const int G = out_size / 4;
    const int N2 = 2 * N;
    const int nb = (N2 + SB - 1) / SB;

    char* p = (char*)d_ws;
    unsigned short* h16 = (unsigned short*)p; p += roundup256((size_t)N2 * FD * 2);
    unsigned short* o16 = (unsigned short*)p; p += roundup256((size_t)N2 * FD * 2);
    int* esorted = (int*)p;   p += roundup256((size_t)2 * E * 4);
    float* als  = (float*)p;  p += roundup256((size_t)N2 * 4);
    float* ald  = (float*)p;  p += roundup256((size_t)N2 * 4);
    int* rowptr = (int*)p;    p += roundup256((size_t)(N2 + 1) * 4);
    int* deg    = (int*)p;    p += roundup256((size_t)N2 * 4);
    int* bsum   = (int*)p;    p += roundup256((size_t)SB * 4);
    unsigned short* wfrag = (unsigned short*)p; p += roundup256((size_t)4 * 16384 * 2);
    float* pooled_td = (float*)p; p += roundup256((size_t)G * FD * 4);
    float* pooled_bu = (float*)p; p += roundup256((size_t)G * FD * 4);
    // erank aliases o16: only live between hist and scatter, before o16's first write
    int* erank = (int*)o16;

    const dim3 blk256(256);
    const dim3 gGemm((N + 63) / 64, 2);
    const dim3 gAgg((N2 * 32 + 255) / 256);
    const dim3 gE2((2 * E + 255) / 256);

    // W prep: td_W1, bu_W1, td_W2, bu_W2 -> wfrag[0..3]
    wprep_kernel<<<dim3(64, 4), blk256, 0, stream>>>(td_W1, bu_W1, td_W2, bu_W2, wfrag);

    // fused CSR (both branches)
    hipMemsetAsync(deg, 0, (size_t)N2 * 4, stream);
    hist_rank_kernel<<<gE2, blk256, 0, stream>>>(td_ei, bu_ei, deg, erank, E, N);
    scan_block_kernel<<<dim3(nb), dim3(SB), 0, stream>>>(deg, rowptr, bsum, N2);
    scan_top_kernel<<<dim3(1), dim3(SB), 0, stream>>>(bsum, nb);
    scan_add_kernel<<<dim3(nb), dim3(SB), 0, stream>>>(rowptr, bsum, N2, 2 * E);
    csr_scatter_kernel<<<gE2, blk256, 0, stream>>>(td_ei, bu_ei, rowptr, erank, esorted, E, N);

    // layer 1: x(f32, shared) -> h16(2N) -> o16(2N)   [o16 write kills erank]
    gemm_mfma_kernel<true><<<gGemm, blk256, 0, stream>>>(
        x, (const unsigned short*)nullptr, wfrag,
        td_as1, td_ad1, bu_as1, bu_ad1, h16, als, ald, N, 0);
    gat_aggregate_kernel<<<gAgg, blk256, 0, stream>>>(
        rowptr, esorted, als, ald, h16, td_b1, bu_b1, o16, N2, N);

    // layer 2: o16 -> h16 -> o16
    gemm_mfma_kernel<false><<<gGemm, blk256, 0, stream>>>(
        (const float*)nullptr, o16, wfrag + 2 * 16384,
        td_as2, td_ad2, bu_as2, bu_ad2, h16, als, ald, N, N);
    gat_aggregate_kernel<<<gAgg, blk256, 0, stream>>>(
        rowptr, esorted, als, ald, h16, td_b2, bu_b2, o16, N2, N);

    // pool (both branches) + fc
    pool_mean_kernel<<<dim3(G, 2), blk256, 0, stream>>>(o16, batch, pooled_td, pooled_bu, N);
    fc_logsoftmax_kernel<<<dim3((G + 3) / 4), blk256, 0, stream>>>(
        pooled_bu, pooled_td, fc_W, fc_b, (float*)d_out, G);
}